// Round 18
// baseline (261.333 us; speedup 1.0000x reference)
//
#include <hip/hip_runtime.h>
#include <hip/hip_bf16.h>

#define B_SZ    2
#define L_SEQ   2048
#define D_MODEL 384
#define D_INNER 768
#define D_STATE 16
#define DT_RANK 24
#define ML      (B_SZ * L_SEQ)   // 4096 rows
#define NCHUNK  64
#define CHLEN   (L_SEQ / NCHUNK) // 32

typedef __hip_bfloat16 bf16;
typedef __attribute__((ext_vector_type(8))) short bf16x8;
typedef __attribute__((ext_vector_type(4))) float f32x4;
typedef __attribute__((ext_vector_type(8))) float f32x8;

// ---------------------------------------------------------------------------
// MFMA bf16 GEMM (R16-verbatim, green). C(MxN) = A(MxK) * W(KxN), W fp32.
// AMODE 0: A fp32 row-major [M][K] (in_proj).  AMODE 1: A bf16 transposed [K][M].
// EPI 0: in_proj split, transposed: outb0[n][m]=xp_raw, outb1[n-768][m]=silu(z)
// EPI 1: outf = fp32 C row-major (ld=N, guard n<N)
// ---------------------------------------------------------------------------
template<int EPI, int AMODE>
__global__ __launch_bounds__(256)
void gemm_mfma(const float* __restrict__ Af, const bf16* __restrict__ At,
               const float* __restrict__ W,
               bf16* __restrict__ outb0, bf16* __restrict__ outb1,
               float* __restrict__ outf, int M, int N, int K)
{
    __shared__ __attribute__((aligned(16))) short As[64][72];
    __shared__ __attribute__((aligned(16))) short Bs[64][72];
    const int tid  = threadIdx.x;
    const int lane = tid & 63;
    const int wave = tid >> 6;
    const int wm   = (wave & 1) * 32;
    const int wn   = (wave >> 1) * 32;
    const int m0   = blockIdx.y * 64;
    const int n0   = blockIdx.x * 64;

    f32x4 acc[2][2];
#pragma unroll
    for (int i = 0; i < 2; i++)
#pragma unroll
        for (int j = 0; j < 2; j++)
#pragma unroll
            for (int r = 0; r < 4; r++) acc[i][j][r] = 0.f;

    for (int kt = 0; kt < K; kt += 64) {
        __syncthreads();
        // Stage A tile 64x64
#pragma unroll
        for (int i = 0; i < 2; i++) {
            int c = tid + 256 * i;
            if (AMODE == 0) {                    // fp32 row-major
                int m = c >> 3, k8 = (c & 7) * 8;
                f32x8 a = *(const f32x8*)&Af[(size_t)(m0 + m) * K + kt + k8];
                bf16x8 h;
#pragma unroll
                for (int j = 0; j < 8; j++)
                    h[j] = (short)__bfloat16_as_ushort(__float2bfloat16(a[j]));
                *(bf16x8*)&As[m][k8] = h;
            } else {                             // bf16 transposed [K][M]
                int m8 = (c & 7) * 8, k = c >> 3;
                bf16x8 a = *(const bf16x8*)&At[(size_t)(kt + k) * M + m0 + m8];
#pragma unroll
                for (int j = 0; j < 8; j++) As[m8 + j][k] = a[j];
            }
        }
        // Stage W tile 64x64 transposed into Bs[n][k], fp32 -> bf16
#pragma unroll
        for (int i = 0; i < 2; i++) {
            int c = tid + 256 * i;
            int n8 = (c & 7) * 8, k = c >> 3;
            if (n0 + n8 + 8 <= N) {
                f32x8 w = *(const f32x8*)&W[(size_t)(kt + k) * N + n0 + n8];
#pragma unroll
                for (int j = 0; j < 8; j++)
                    Bs[n8 + j][k] = (short)__bfloat16_as_ushort(__float2bfloat16(w[j]));
            } else {
#pragma unroll
                for (int j = 0; j < 8; j++) Bs[n8 + j][k] = 0;
            }
        }
        __syncthreads();
#pragma unroll
        for (int ks = 0; ks < 2; ks++) {
            int kb = ks * 32 + (lane >> 4) * 8;
            bf16x8 a0 = *(const bf16x8*)&As[wm + (lane & 15)][kb];
            bf16x8 a1 = *(const bf16x8*)&As[wm + 16 + (lane & 15)][kb];
            bf16x8 b0 = *(const bf16x8*)&Bs[wn + (lane & 15)][kb];
            bf16x8 b1 = *(const bf16x8*)&Bs[wn + 16 + (lane & 15)][kb];
            acc[0][0] = __builtin_amdgcn_mfma_f32_16x16x32_bf16(a0, b0, acc[0][0], 0, 0, 0);
            acc[0][1] = __builtin_amdgcn_mfma_f32_16x16x32_bf16(a0, b1, acc[0][1], 0, 0, 0);
            acc[1][0] = __builtin_amdgcn_mfma_f32_16x16x32_bf16(a1, b0, acc[1][0], 0, 0, 0);
            acc[1][1] = __builtin_amdgcn_mfma_f32_16x16x32_bf16(a1, b1, acc[1][1], 0, 0, 0);
        }
    }

#pragma unroll
    for (int am = 0; am < 2; am++)
#pragma unroll
        for (int bn = 0; bn < 2; bn++)
#pragma unroll
            for (int r = 0; r < 4; r++) {
                int m = m0 + wm + am * 16 + (lane >> 4) * 4 + r;
                int n = n0 + wn + bn * 16 + (lane & 15);
                float v = acc[am][bn][r];
                if (EPI == 0) {
                    if (n < D_INNER)
                        outb0[(size_t)n * ML + m] = __float2bfloat16(v);
                    else
                        outb1[(size_t)(n - D_INNER) * ML + m] =
                            __float2bfloat16(v / (1.f + __expf(-v)));
                } else {
                    if (n < N) outf[(size_t)m * N + n] = v;
                }
            }
}

// ---------------------------------------------------------------------------
// x_proj GEMM with K-split x4 (R14/R16-verbatim, green): grid (4, ML/64).
// Partial over K in [kc*192, kc*192+192), atomicAdd fp32 into x_dbl.
// ---------------------------------------------------------------------------
__global__ __launch_bounds__(256)
void gemm_xproj_split(const bf16* __restrict__ At, const float* __restrict__ W,
                      float* __restrict__ outf, int M, int N, int K)
{
    __shared__ __attribute__((aligned(16))) short As[64][72];
    __shared__ __attribute__((aligned(16))) short Bs[64][72];
    const int tid  = threadIdx.x;
    const int lane = tid & 63;
    const int wave = tid >> 6;
    const int wm   = (wave & 1) * 32;
    const int wn   = (wave >> 1) * 32;
    const int m0   = blockIdx.y * 64;
    const int k0   = blockIdx.x * (768 / 4);     // 192-wide K chunk

    f32x4 acc[2][2];
#pragma unroll
    for (int i = 0; i < 2; i++)
#pragma unroll
        for (int j = 0; j < 2; j++)
#pragma unroll
            for (int r = 0; r < 4; r++) acc[i][j][r] = 0.f;

    for (int kt = k0; kt < k0 + 192; kt += 64) {
        __syncthreads();
#pragma unroll
        for (int i = 0; i < 2; i++) {
            int c = tid + 256 * i;
            int m8 = (c & 7) * 8, k = c >> 3;
            bf16x8 a = *(const bf16x8*)&At[(size_t)(kt + k) * M + m0 + m8];
#pragma unroll
            for (int j = 0; j < 8; j++) As[m8 + j][k] = a[j];
        }
#pragma unroll
        for (int i = 0; i < 2; i++) {
            int c = tid + 256 * i;
            int n8 = (c & 7) * 8, k = c >> 3;
            if (n8 + 8 <= N) {
                f32x8 w = *(const f32x8*)&W[(size_t)(kt + k) * N + n8];
#pragma unroll
                for (int j = 0; j < 8; j++)
                    Bs[n8 + j][k] = (short)__bfloat16_as_ushort(__float2bfloat16(w[j]));
            } else {
#pragma unroll
                for (int j = 0; j < 8; j++) Bs[n8 + j][k] = 0;
            }
        }
        __syncthreads();
#pragma unroll
        for (int ks = 0; ks < 2; ks++) {
            int kb = ks * 32 + (lane >> 4) * 8;
            bf16x8 a0 = *(const bf16x8*)&As[wm + (lane & 15)][kb];
            bf16x8 a1 = *(const bf16x8*)&As[wm + 16 + (lane & 15)][kb];
            bf16x8 b0 = *(const bf16x8*)&Bs[wn + (lane & 15)][kb];
            bf16x8 b1 = *(const bf16x8*)&Bs[wn + 16 + (lane & 15)][kb];
            acc[0][0] = __builtin_amdgcn_mfma_f32_16x16x32_bf16(a0, b0, acc[0][0], 0, 0, 0);
            acc[0][1] = __builtin_amdgcn_mfma_f32_16x16x32_bf16(a0, b1, acc[0][1], 0, 0, 0);
            acc[1][0] = __builtin_amdgcn_mfma_f32_16x16x32_bf16(a1, b0, acc[1][0], 0, 0, 0);
            acc[1][1] = __builtin_amdgcn_mfma_f32_16x16x32_bf16(a1, b1, acc[1][1], 0, 0, 0);
        }
    }

#pragma unroll
    for (int am = 0; am < 2; am++)
#pragma unroll
        for (int bn = 0; bn < 2; bn++)
#pragma unroll
            for (int r = 0; r < 4; r++) {
                int m = m0 + wm + am * 16 + (lane >> 4) * 4 + r;
                int n = wn + bn * 16 + (lane & 15);
                if (n < N)
                    atomicAdd(&outf[(size_t)m * N + n], acc[am][bn][r]);
            }
}

// ---------------------------------------------------------------------------
// out_proj GEMM with K-split x4 (same green structure as gemm_xproj_split):
// grid (4*6, ML/64); blockIdx.x = (nb<<2)|kc. Each block: K in
// [kc*192, kc*192+192), N-tile nb*64. atomicAdd fp32 into d_out (memset 0).
// Fixes out_proj's 384-block / 12-serial-K-iter latency exposure (same
// disease x_proj had before R14).
// ---------------------------------------------------------------------------
__global__ __launch_bounds__(256)
void gemm_outproj_split(const bf16* __restrict__ At, const float* __restrict__ W,
                        float* __restrict__ outf, int M, int N, int K)
{
    __shared__ __attribute__((aligned(16))) short As[64][72];
    __shared__ __attribute__((aligned(16))) short Bs[64][72];
    const int tid  = threadIdx.x;
    const int lane = tid & 63;
    const int wave = tid >> 6;
    const int wm   = (wave & 1) * 32;
    const int wn   = (wave >> 1) * 32;
    const int m0   = blockIdx.y * 64;
    const int k0   = (blockIdx.x & 3) * (768 / 4);   // 192-wide K chunk
    const int n0   = (blockIdx.x >> 2) * 64;         // N tile (0..5)

    f32x4 acc[2][2];
#pragma unroll
    for (int i = 0; i < 2; i++)
#pragma unroll
        for (int j = 0; j < 2; j++)
#pragma unroll
            for (int r = 0; r < 4; r++) acc[i][j][r] = 0.f;

    for (int kt = k0; kt < k0 + 192; kt += 64) {
        __syncthreads();
#pragma unroll
        for (int i = 0; i < 2; i++) {
            int c = tid + 256 * i;
            int m8 = (c & 7) * 8, k = c >> 3;
            bf16x8 a = *(const bf16x8*)&At[(size_t)(kt + k) * M + m0 + m8];
#pragma unroll
            for (int j = 0; j < 8; j++) As[m8 + j][k] = a[j];
        }
#pragma unroll
        for (int i = 0; i < 2; i++) {
            int c = tid + 256 * i;
            int n8 = (c & 7) * 8, k = c >> 3;
            f32x8 w = *(const f32x8*)&W[(size_t)(kt + k) * N + n0 + n8];
#pragma unroll
            for (int j = 0; j < 8; j++)
                Bs[n8 + j][k] = (short)__bfloat16_as_ushort(__float2bfloat16(w[j]));
        }
        __syncthreads();
#pragma unroll
        for (int ks = 0; ks < 2; ks++) {
            int kb = ks * 32 + (lane >> 4) * 8;
            bf16x8 a0 = *(const bf16x8*)&As[wm + (lane & 15)][kb];
            bf16x8 a1 = *(const bf16x8*)&As[wm + 16 + (lane & 15)][kb];
            bf16x8 b0 = *(const bf16x8*)&Bs[wn + (lane & 15)][kb];
            bf16x8 b1 = *(const bf16x8*)&Bs[wn + 16 + (lane & 15)][kb];
            acc[0][0] = __builtin_amdgcn_mfma_f32_16x16x32_bf16(a0, b0, acc[0][0], 0, 0, 0);
            acc[0][1] = __builtin_amdgcn_mfma_f32_16x16x32_bf16(a0, b1, acc[0][1], 0, 0, 0);
            acc[1][0] = __builtin_amdgcn_mfma_f32_16x16x32_bf16(a1, b0, acc[1][0], 0, 0, 0);
            acc[1][1] = __builtin_amdgcn_mfma_f32_16x16x32_bf16(a1, b1, acc[1][1], 0, 0, 0);
        }
    }

#pragma unroll
    for (int am = 0; am < 2; am++)
#pragma unroll
        for (int bn = 0; bn < 2; bn++)
#pragma unroll
            for (int r = 0; r < 4; r++) {
                int m = m0 + wm + am * 16 + (lane >> 4) * 4 + r;
                int n = n0 + wn + bn * 16 + (lane & 15);
                atomicAdd(&outf[(size_t)m * N + n], acc[am][bn][r]);
            }
}

// ---------------------------------------------------------------------------
// Causal depthwise conv (K=4) + bias + SiLU on [d][ml]. (R16-verbatim)
// ---------------------------------------------------------------------------
__global__ __launch_bounds__(256)
void conv_silu_kernel(const bf16* __restrict__ xp_raw_t,
                      const float* __restrict__ cw, const float* __restrict__ cb,
                      bf16* __restrict__ xp_t)
{
    const int ml = blockIdx.x * 256 + threadIdx.x;
    const int d  = blockIdx.y;
    const int l  = ml & (L_SEQ - 1);
    const size_t row = (size_t)d * ML;
    float s = cb[d];
#pragma unroll
    for (int j = 0; j < 4; j++) {
        if (l - 3 + j >= 0)
            s += __bfloat162float(xp_raw_t[row + ml - 3 + j]) * cw[d * 4 + j];
    }
    float act = s / (1.f + __expf(-s));                 // silu
    xp_t[row + ml] = __float2bfloat16(act);
}

// ---------------------------------------------------------------------------
// dt = softplus(dt_r @ dt_proj_w + b), LDS-tiled (R16-verbatim): 64m x 48d.
// ---------------------------------------------------------------------------
__global__ __launch_bounds__(256)
void dt_kernel(const float* __restrict__ x_dbl, const float* __restrict__ dtw,
               const float* __restrict__ dtb, bf16* __restrict__ dt_t)
{
    __shared__ float xs[64 * 25];
    __shared__ float ws[24 * 48];
    const int tid = threadIdx.x;
    const int m0 = blockIdx.x * 64;
    const int d0 = blockIdx.y * 48;
#pragma unroll
    for (int i = 0; i < 6; i++) {
        int idx = tid + 256 * i;        // < 1536 = 64*24
        int r_ = idx / 24, cc = idx % 24;
        xs[r_ * 25 + cc] = x_dbl[(size_t)(m0 + r_) * 56 + cc];
    }
#pragma unroll
    for (int i = 0; i < 5; i++) {
        int idx = tid + 256 * i;
        if (idx < 24 * 48) {
            int r_ = idx / 48, dd = idx % 48;
            ws[idx] = dtw[r_ * D_INNER + d0 + dd];
        }
    }
    __syncthreads();
#pragma unroll
    for (int i = 0; i < 12; i++) {
        int o = tid + 256 * i;          // < 3072 = 64*48
        int mloc = o & 63, dd = o >> 6; // dd wave-uniform
        float acc = dtb[d0 + dd];
#pragma unroll
        for (int r_ = 0; r_ < 24; r_++)
            acc += xs[mloc * 25 + r_] * ws[r_ * 48 + dd];
        float sp = fmaxf(acc, 0.f) + log1pf(__expf(-fabsf(acc)));
        dt_t[(size_t)(d0 + dd) * ML + m0 + mloc] = __float2bfloat16(sp);
    }
}

// ---------------------------------------------------------------------------
// Chunk-parallel selective scan (R16-verbatim, green): bf16x8 group loads,
// Kogge-Stone over chunks, butterfly reduce, lane-0 store.
// ---------------------------------------------------------------------------
__global__ __launch_bounds__(1024)
void scan_kernel(const bf16* __restrict__ dt_t, const bf16* __restrict__ xp_t,
                 const float* __restrict__ x_dbl, const bf16* __restrict__ zs_t,
                 const float* __restrict__ A_log, const float* __restrict__ Dp,
                 bf16* __restrict__ y_t)
{
    __shared__ float sP[NCHUNK][D_STATE];
    __shared__ float sH[NCHUNK][D_STATE];
    const int tid = threadIdx.x;
    const int c = tid >> 4;           // chunk 0..63
    const int n = tid & 15;           // state 0..15
    const int g = blockIdx.x;         // (b,d)
    const int b = g / D_INNER;
    const int d = g % D_INNER;
    const float A = -__expf(A_log[d * D_STATE + n]);
    const size_t base_t = (size_t)d * ML + (size_t)b * L_SEQ + (size_t)c * CHLEN;
    const size_t base_m = (size_t)b * L_SEQ + (size_t)c * CHLEN;

    float h = 0.f, P = 1.f;
#pragma unroll
    for (int g2 = 0; g2 < 2; g2++) {
        bf16x8 vdt0 = *(const bf16x8*)&dt_t[base_t + g2 * 16];
        bf16x8 vdt1 = *(const bf16x8*)&dt_t[base_t + g2 * 16 + 8];
        bf16x8 vxp0 = *(const bf16x8*)&xp_t[base_t + g2 * 16];
        bf16x8 vxp1 = *(const bf16x8*)&xp_t[base_t + g2 * 16 + 8];
#pragma unroll
        for (int k = 0; k < 16; k++) {
            const int j = g2 * 16 + k;
            short sdt = (k < 8) ? vdt0[k & 7] : vdt1[k & 7];
            short sxp = (k < 8) ? vxp0[k & 7] : vxp1[k & 7];
            float dtv = __uint_as_float(((unsigned)(unsigned short)sdt) << 16);
            float xpv = __uint_as_float(((unsigned)(unsigned short)sxp) << 16);
            float Bn  = x_dbl[(base_m + j) * 56 + DT_RANK + n];
            float aj = __expf(dtv * A);
            h = aj * h + Bn * (dtv * xpv);
            P *= aj;
        }
    }
    sP[c][n] = P;
    sH[c][n] = h;
    __syncthreads();

    // Kogge-Stone inclusive scan over chunks: compose (P,h) pairs
#pragma unroll
    for (int s = 1; s < NCHUNK; s <<= 1) {
        float p2 = 0.f, h2 = 0.f;
        const bool act = (c >= s);
        if (act) { p2 = sP[c - s][n]; h2 = sH[c - s][n]; }
        __syncthreads();
        if (act) {
            sH[c][n] = sP[c][n] * h2 + sH[c][n];
            sP[c][n] = sP[c][n] * p2;
        }
        __syncthreads();
    }
    const float hinit = (c == 0) ? 0.f : sH[c - 1][n];

    // Phase 3: corrected re-scan (recompute a,u) + butterfly reduce + store
    const float Dd = Dp[d];
    h = hinit;
#pragma unroll
    for (int g2 = 0; g2 < 2; g2++) {
        bf16x8 vdt0 = *(const bf16x8*)&dt_t[base_t + g2 * 16];
        bf16x8 vdt1 = *(const bf16x8*)&dt_t[base_t + g2 * 16 + 8];
        bf16x8 vxp0 = *(const bf16x8*)&xp_t[base_t + g2 * 16];
        bf16x8 vxp1 = *(const bf16x8*)&xp_t[base_t + g2 * 16 + 8];
#pragma unroll
        for (int k = 0; k < 16; k++) {
            const int j = g2 * 16 + k;
            short sdt = (k < 8) ? vdt0[k & 7] : vdt1[k & 7];
            short sxp = (k < 8) ? vxp0[k & 7] : vxp1[k & 7];
            float dtv = __uint_as_float(((unsigned)(unsigned short)sdt) << 16);
            float xpv = __uint_as_float(((unsigned)(unsigned short)sxp) << 16);
            float Bn  = x_dbl[(base_m + j) * 56 + DT_RANK + n];
            float aj = __expf(dtv * A);
            h = aj * h + Bn * (dtv * xpv);
            float Cn = x_dbl[(base_m + j) * 56 + DT_RANK + D_STATE + n];
            float yv = h * Cn;
            yv += __shfl_xor(yv, 1);
            yv += __shfl_xor(yv, 2);
            yv += __shfl_xor(yv, 4);
            yv += __shfl_xor(yv, 8);
            if (n == 0) {
                float y = (yv + xpv * Dd) * __bfloat162float(zs_t[base_t + j]);
                y_t[base_t + j] = __float2bfloat16(y);
            }
        }
    }
}

// ---------------------------------------------------------------------------
extern "C" void kernel_launch(void* const* d_in, const int* in_sizes, int n_in,
                              void* d_out, int out_size, void* d_ws, size_t ws_size,
                              hipStream_t stream)
{
    const float* x         = (const float*)d_in[0];
    const float* in_proj_w = (const float*)d_in[1];
    const float* conv_w    = (const float*)d_in[2];
    const float* conv_b    = (const float*)d_in[3];
    const float* x_proj_w  = (const float*)d_in[4];
    const float* dt_proj_w = (const float*)d_in[5];
    const float* dt_proj_b = (const float*)d_in[6];
    const float* A_log     = (const float*)d_in[7];
    const float* Dvec      = (const float*)d_in[8];
    const float* out_proj_w= (const float*)d_in[9];

    // workspace (all transposed [d][ml] bf16 except x_dbl): ~26.1 MB
    bf16* xp_raw_t = (bf16*)d_ws;                        // [768][ML] (reused as y_t)
    bf16* zs_t     = xp_raw_t + (size_t)ML * D_INNER;    // [768][ML] silu(z)
    bf16* xp_t     = zs_t     + (size_t)ML * D_INNER;    // [768][ML]
    bf16* dt_t     = xp_t     + (size_t)ML * D_INNER;    // [768][ML]
    float* x_dbl   = (float*)(dt_t + (size_t)ML * D_INNER); // [ML][56] fp32
    bf16* y_t      = xp_raw_t;                           // alias (dead after conv)

    dim3 blk(256);

    // 1) in_proj (64x64, proven): -> xp_raw_t | zs_t (transposed)
    gemm_mfma<0, 0><<<dim3(2 * D_INNER / 64, ML / 64), blk, 0, stream>>>(
        x, nullptr, in_proj_w, xp_raw_t, zs_t, nullptr, ML, 2 * D_INNER, D_MODEL);

    // 2) depthwise causal conv + silu
    conv_silu_kernel<<<dim3(ML / 256, D_INNER), blk, 0, stream>>>(
        xp_raw_t, conv_w, conv_b, xp_t);

    // 3) x_proj, K-split x4 with fp32 atomics (x_dbl zeroed first)
    hipMemsetAsync(x_dbl, 0, (size_t)ML * 56 * sizeof(float), stream);
    gemm_xproj_split<<<dim3(4, ML / 64), blk, 0, stream>>>(
        xp_t, x_proj_w, x_dbl, ML, 56, D_INNER);

    // 4) dt_proj + softplus (LDS-tiled) -> dt_t
    dt_kernel<<<dim3(ML / 64, D_INNER / 48), blk, 0, stream>>>(
        x_dbl, dt_proj_w, dt_proj_b, dt_t);

    // 5) chunk-parallel selective scan -> y_t (aliases xp_raw_t)
    scan_kernel<<<B_SZ * D_INNER, 1024, 0, stream>>>(
        dt_t, xp_t, x_dbl, zs_t, A_log, Dvec, y_t);

    // 6) out_proj, K-split x4 (d_out zeroed first; harness poisons it)
    hipMemsetAsync(d_out, 0, (size_t)out_size * sizeof(float), stream);
    gemm_outproj_split<<<dim3(4 * (D_MODEL / 64), ML / 64), blk, 0, stream>>>(
        y_t, out_proj_w, (float*)d_out, ML, D_MODEL, D_INNER);
}

// Round 20
// 258.923 us; speedup vs baseline: 1.0093x; 1.0093x over previous
//
#include <hip/hip_runtime.h>
#include <hip/hip_bf16.h>

#define B_SZ    2
#define L_SEQ   2048
#define D_MODEL 384
#define D_INNER 768
#define D_STATE 16
#define DT_RANK 24
#define ML      (B_SZ * L_SEQ)   // 4096 rows
#define NCHUNK  64
#define CHLEN   (L_SEQ / NCHUNK) // 32

typedef __hip_bfloat16 bf16;
typedef __attribute__((ext_vector_type(8))) short bf16x8;
typedef __attribute__((ext_vector_type(4))) float f32x4;
typedef __attribute__((ext_vector_type(8))) float f32x8;

// ---------------------------------------------------------------------------
// MFMA bf16 GEMM (R12/R14-verbatim, green). C(MxN) = A(MxK) * W(KxN), W fp32.
// AMODE 0: A fp32 row-major [M][K] (in_proj).  AMODE 1: A bf16 transposed [K][M].
// 256 thr / 4 waves; tile 64x64, BK=64; wave = 32x32 via 2x2 16x16x32 MFMA.
// EPI 0: in_proj split, transposed: outb0[n][m]=xp_raw, outb1[n-768][m]=silu(z)
// EPI 1: outf = fp32 C row-major (ld=N, guard n<N)
// ---------------------------------------------------------------------------
template<int EPI, int AMODE>
__global__ __launch_bounds__(256)
void gemm_mfma(const float* __restrict__ Af, const bf16* __restrict__ At,
               const float* __restrict__ W,
               bf16* __restrict__ outb0, bf16* __restrict__ outb1,
               float* __restrict__ outf, int M, int N, int K)
{
    __shared__ __attribute__((aligned(16))) short As[64][72];
    __shared__ __attribute__((aligned(16))) short Bs[64][72];
    const int tid  = threadIdx.x;
    const int lane = tid & 63;
    const int wave = tid >> 6;
    const int wm   = (wave & 1) * 32;
    const int wn   = (wave >> 1) * 32;
    const int m0   = blockIdx.y * 64;
    const int n0   = blockIdx.x * 64;

    f32x4 acc[2][2];
#pragma unroll
    for (int i = 0; i < 2; i++)
#pragma unroll
        for (int j = 0; j < 2; j++)
#pragma unroll
            for (int r = 0; r < 4; r++) acc[i][j][r] = 0.f;

    for (int kt = 0; kt < K; kt += 64) {
        __syncthreads();
        // Stage A tile 64x64
#pragma unroll
        for (int i = 0; i < 2; i++) {
            int c = tid + 256 * i;
            if (AMODE == 0) {                    // fp32 row-major
                int m = c >> 3, k8 = (c & 7) * 8;
                f32x8 a = *(const f32x8*)&Af[(size_t)(m0 + m) * K + kt + k8];
                bf16x8 h;
#pragma unroll
                for (int j = 0; j < 8; j++)
                    h[j] = (short)__bfloat16_as_ushort(__float2bfloat16(a[j]));
                *(bf16x8*)&As[m][k8] = h;
            } else {                             // bf16 transposed [K][M]
                int m8 = (c & 7) * 8, k = c >> 3;
                bf16x8 a = *(const bf16x8*)&At[(size_t)(kt + k) * M + m0 + m8];
#pragma unroll
                for (int j = 0; j < 8; j++) As[m8 + j][k] = a[j];
            }
        }
        // Stage W tile 64x64 transposed into Bs[n][k], fp32 -> bf16
#pragma unroll
        for (int i = 0; i < 2; i++) {
            int c = tid + 256 * i;
            int n8 = (c & 7) * 8, k = c >> 3;
            if (n0 + n8 + 8 <= N) {
                f32x8 w = *(const f32x8*)&W[(size_t)(kt + k) * N + n0 + n8];
#pragma unroll
                for (int j = 0; j < 8; j++)
                    Bs[n8 + j][k] = (short)__bfloat16_as_ushort(__float2bfloat16(w[j]));
            } else {
#pragma unroll
                for (int j = 0; j < 8; j++) Bs[n8 + j][k] = 0;
            }
        }
        __syncthreads();
#pragma unroll
        for (int ks = 0; ks < 2; ks++) {
            int kb = ks * 32 + (lane >> 4) * 8;
            bf16x8 a0 = *(const bf16x8*)&As[wm + (lane & 15)][kb];
            bf16x8 a1 = *(const bf16x8*)&As[wm + 16 + (lane & 15)][kb];
            bf16x8 b0 = *(const bf16x8*)&Bs[wn + (lane & 15)][kb];
            bf16x8 b1 = *(const bf16x8*)&Bs[wn + 16 + (lane & 15)][kb];
            acc[0][0] = __builtin_amdgcn_mfma_f32_16x16x32_bf16(a0, b0, acc[0][0], 0, 0, 0);
            acc[0][1] = __builtin_amdgcn_mfma_f32_16x16x32_bf16(a0, b1, acc[0][1], 0, 0, 0);
            acc[1][0] = __builtin_amdgcn_mfma_f32_16x16x32_bf16(a1, b0, acc[1][0], 0, 0, 0);
            acc[1][1] = __builtin_amdgcn_mfma_f32_16x16x32_bf16(a1, b1, acc[1][1], 0, 0, 0);
        }
    }

#pragma unroll
    for (int am = 0; am < 2; am++)
#pragma unroll
        for (int bn = 0; bn < 2; bn++)
#pragma unroll
            for (int r = 0; r < 4; r++) {
                int m = m0 + wm + am * 16 + (lane >> 4) * 4 + r;
                int n = n0 + wn + bn * 16 + (lane & 15);
                float v = acc[am][bn][r];
                if (EPI == 0) {
                    if (n < D_INNER)
                        outb0[(size_t)n * ML + m] = __float2bfloat16(v);
                    else
                        outb1[(size_t)(n - D_INNER) * ML + m] =
                            __float2bfloat16(v / (1.f + __expf(-v)));
                } else {
                    if (n < N) outf[(size_t)m * N + n] = v;
                }
            }
}

// ---------------------------------------------------------------------------
// x_proj GEMM with K-split x4 (R14-verbatim, green): grid (4, ML/64).
// Partial over K in [kc*192, kc*192+192), atomicAdd fp32 into x_dbl.
// ---------------------------------------------------------------------------
__global__ __launch_bounds__(256)
void gemm_xproj_split(const bf16* __restrict__ At, const float* __restrict__ W,
                      float* __restrict__ outf, int M, int N, int K)
{
    __shared__ __attribute__((aligned(16))) short As[64][72];
    __shared__ __attribute__((aligned(16))) short Bs[64][72];
    const int tid  = threadIdx.x;
    const int lane = tid & 63;
    const int wave = tid >> 6;
    const int wm   = (wave & 1) * 32;
    const int wn   = (wave >> 1) * 32;
    const int m0   = blockIdx.y * 64;
    const int k0   = blockIdx.x * (768 / 4);     // 192-wide K chunk

    f32x4 acc[2][2];
#pragma unroll
    for (int i = 0; i < 2; i++)
#pragma unroll
        for (int j = 0; j < 2; j++)
#pragma unroll
            for (int r = 0; r < 4; r++) acc[i][j][r] = 0.f;

    for (int kt = k0; kt < k0 + 192; kt += 64) {
        __syncthreads();
#pragma unroll
        for (int i = 0; i < 2; i++) {
            int c = tid + 256 * i;
            int m8 = (c & 7) * 8, k = c >> 3;
            bf16x8 a = *(const bf16x8*)&At[(size_t)(kt + k) * M + m0 + m8];
#pragma unroll
            for (int j = 0; j < 8; j++) As[m8 + j][k] = a[j];
        }
#pragma unroll
        for (int i = 0; i < 2; i++) {
            int c = tid + 256 * i;
            int n8 = (c & 7) * 8, k = c >> 3;
            if (n8 + 8 <= N) {
                f32x8 w = *(const f32x8*)&W[(size_t)(kt + k) * N + n8];
#pragma unroll
                for (int j = 0; j < 8; j++)
                    Bs[n8 + j][k] = (short)__bfloat16_as_ushort(__float2bfloat16(w[j]));
            } else {
#pragma unroll
                for (int j = 0; j < 8; j++) Bs[n8 + j][k] = 0;
            }
        }
        __syncthreads();
#pragma unroll
        for (int ks = 0; ks < 2; ks++) {
            int kb = ks * 32 + (lane >> 4) * 8;
            bf16x8 a0 = *(const bf16x8*)&As[wm + (lane & 15)][kb];
            bf16x8 a1 = *(const bf16x8*)&As[wm + 16 + (lane & 15)][kb];
            bf16x8 b0 = *(const bf16x8*)&Bs[wn + (lane & 15)][kb];
            bf16x8 b1 = *(const bf16x8*)&Bs[wn + 16 + (lane & 15)][kb];
            acc[0][0] = __builtin_amdgcn_mfma_f32_16x16x32_bf16(a0, b0, acc[0][0], 0, 0, 0);
            acc[0][1] = __builtin_amdgcn_mfma_f32_16x16x32_bf16(a0, b1, acc[0][1], 0, 0, 0);
            acc[1][0] = __builtin_amdgcn_mfma_f32_16x16x32_bf16(a1, b0, acc[1][0], 0, 0, 0);
            acc[1][1] = __builtin_amdgcn_mfma_f32_16x16x32_bf16(a1, b1, acc[1][1], 0, 0, 0);
        }
    }

#pragma unroll
    for (int am = 0; am < 2; am++)
#pragma unroll
        for (int bn = 0; bn < 2; bn++)
#pragma unroll
            for (int r = 0; r < 4; r++) {
                int m = m0 + wm + am * 16 + (lane >> 4) * 4 + r;
                int n = wn + bn * 16 + (lane & 15);
                if (n < N)
                    atomicAdd(&outf[(size_t)m * N + n], acc[am][bn][r]);
            }
}

// ---------------------------------------------------------------------------
// Causal depthwise conv (K=4) + bias + SiLU on [d][ml]. (R12/R14-verbatim)
// ---------------------------------------------------------------------------
__global__ __launch_bounds__(256)
void conv_silu_kernel(const bf16* __restrict__ xp_raw_t,
                      const float* __restrict__ cw, const float* __restrict__ cb,
                      bf16* __restrict__ xp_t)
{
    const int ml = blockIdx.x * 256 + threadIdx.x;
    const int d  = blockIdx.y;
    const int l  = ml & (L_SEQ - 1);
    const size_t row = (size_t)d * ML;
    float s = cb[d];
#pragma unroll
    for (int j = 0; j < 4; j++) {
        if (l - 3 + j >= 0)
            s += __bfloat162float(xp_raw_t[row + ml - 3 + j]) * cw[d * 4 + j];
    }
    float act = s / (1.f + __expf(-s));                 // silu
    xp_t[row + ml] = __float2bfloat16(act);
}

// ---------------------------------------------------------------------------
// dt = softplus(dt_r @ dt_proj_w + b), LDS-tiled (R13/R14-green): 64m x 48d.
// ---------------------------------------------------------------------------
__global__ __launch_bounds__(256)
void dt_kernel(const float* __restrict__ x_dbl, const float* __restrict__ dtw,
               const float* __restrict__ dtb, bf16* __restrict__ dt_t)
{
    __shared__ float xs[64 * 25];
    __shared__ float ws[24 * 48];
    const int tid = threadIdx.x;
    const int m0 = blockIdx.x * 64;
    const int d0 = blockIdx.y * 48;
#pragma unroll
    for (int i = 0; i < 6; i++) {
        int idx = tid + 256 * i;        // < 1536 = 64*24
        int r_ = idx / 24, cc = idx % 24;
        xs[r_ * 25 + cc] = x_dbl[(size_t)(m0 + r_) * 56 + cc];
    }
#pragma unroll
    for (int i = 0; i < 5; i++) {
        int idx = tid + 256 * i;
        if (idx < 24 * 48) {
            int r_ = idx / 48, dd = idx % 48;
            ws[idx] = dtw[r_ * D_INNER + d0 + dd];
        }
    }
    __syncthreads();
#pragma unroll
    for (int i = 0; i < 12; i++) {
        int o = tid + 256 * i;          // < 3072 = 64*48
        int mloc = o & 63, dd = o >> 6; // dd wave-uniform
        float acc = dtb[d0 + dd];
#pragma unroll
        for (int r_ = 0; r_ < 24; r_++)
            acc += xs[mloc * 25 + r_] * ws[r_ * 48 + dd];
        float sp = fmaxf(acc, 0.f) + log1pf(__expf(-fabsf(acc)));
        dt_t[(size_t)(d0 + dd) * ML + m0 + mloc] = __float2bfloat16(sp);
    }
}

// ---------------------------------------------------------------------------
// Chunk-parallel selective scan. R14-green structure; dt/xp loads widened to
// bf16x8 pairs per 16-step sub-group (16 VGPRs live within a group only —
// R8's spill came from 48 regs live across the whole phase).
// Element extracts use compile-time indices under full unroll.
// ---------------------------------------------------------------------------
__global__ __launch_bounds__(1024)
void scan_kernel(const bf16* __restrict__ dt_t, const bf16* __restrict__ xp_t,
                 const float* __restrict__ x_dbl, const bf16* __restrict__ zs_t,
                 const float* __restrict__ A_log, const float* __restrict__ Dp,
                 bf16* __restrict__ y_t)
{
    __shared__ float sP[NCHUNK][D_STATE];
    __shared__ float sH[NCHUNK][D_STATE];
    const int tid = threadIdx.x;
    const int c = tid >> 4;           // chunk 0..63
    const int n = tid & 15;           // state 0..15
    const int g = blockIdx.x;         // (b,d)
    const int b = g / D_INNER;
    const int d = g % D_INNER;
    const float A = -__expf(A_log[d * D_STATE + n]);
    const size_t base_t = (size_t)d * ML + (size_t)b * L_SEQ + (size_t)c * CHLEN;
    const size_t base_m = (size_t)b * L_SEQ + (size_t)c * CHLEN;

    float h = 0.f, P = 1.f;
#pragma unroll
    for (int g2 = 0; g2 < 2; g2++) {
        bf16x8 vdt0 = *(const bf16x8*)&dt_t[base_t + g2 * 16];
        bf16x8 vdt1 = *(const bf16x8*)&dt_t[base_t + g2 * 16 + 8];
        bf16x8 vxp0 = *(const bf16x8*)&xp_t[base_t + g2 * 16];
        bf16x8 vxp1 = *(const bf16x8*)&xp_t[base_t + g2 * 16 + 8];
#pragma unroll
        for (int k = 0; k < 16; k++) {
            const int j = g2 * 16 + k;
            short sdt = (k < 8) ? vdt0[k & 7] : vdt1[k & 7];
            short sxp = (k < 8) ? vxp0[k & 7] : vxp1[k & 7];
            float dtv = __uint_as_float(((unsigned)(unsigned short)sdt) << 16);
            float xpv = __uint_as_float(((unsigned)(unsigned short)sxp) << 16);
            float Bn  = x_dbl[(base_m + j) * 56 + DT_RANK + n];
            float aj = __expf(dtv * A);
            h = aj * h + Bn * (dtv * xpv);
            P *= aj;
        }
    }
    sP[c][n] = P;
    sH[c][n] = h;
    __syncthreads();

    // Kogge-Stone inclusive scan over chunks: compose (P,h) pairs
#pragma unroll
    for (int s = 1; s < NCHUNK; s <<= 1) {
        float p2 = 0.f, h2 = 0.f;
        const bool act = (c >= s);
        if (act) { p2 = sP[c - s][n]; h2 = sH[c - s][n]; }
        __syncthreads();
        if (act) {
            sH[c][n] = sP[c][n] * h2 + sH[c][n];
            sP[c][n] = sP[c][n] * p2;
        }
        __syncthreads();
    }
    const float hinit = (c == 0) ? 0.f : sH[c - 1][n];

    // Phase 3: corrected re-scan (recompute a,u) + butterfly reduce + store
    const float Dd = Dp[d];
    h = hinit;
#pragma unroll
    for (int g2 = 0; g2 < 2; g2++) {
        bf16x8 vdt0 = *(const bf16x8*)&dt_t[base_t + g2 * 16];
        bf16x8 vdt1 = *(const bf16x8*)&dt_t[base_t + g2 * 16 + 8];
        bf16x8 vxp0 = *(const bf16x8*)&xp_t[base_t + g2 * 16];
        bf16x8 vxp1 = *(const bf16x8*)&xp_t[base_t + g2 * 16 + 8];
#pragma unroll
        for (int k = 0; k < 16; k++) {
            const int j = g2 * 16 + k;
            short sdt = (k < 8) ? vdt0[k & 7] : vdt1[k & 7];
            short sxp = (k < 8) ? vxp0[k & 7] : vxp1[k & 7];
            float dtv = __uint_as_float(((unsigned)(unsigned short)sdt) << 16);
            float xpv = __uint_as_float(((unsigned)(unsigned short)sxp) << 16);
            float Bn  = x_dbl[(base_m + j) * 56 + DT_RANK + n];
            float aj = __expf(dtv * A);
            h = aj * h + Bn * (dtv * xpv);
            float Cn = x_dbl[(base_m + j) * 56 + DT_RANK + D_STATE + n];
            float yv = h * Cn;
            yv += __shfl_xor(yv, 1);
            yv += __shfl_xor(yv, 2);
            yv += __shfl_xor(yv, 4);
            yv += __shfl_xor(yv, 8);
            if (n == 0) {
                float y = (yv + xpv * Dd) * __bfloat162float(zs_t[base_t + j]);
                y_t[base_t + j] = __float2bfloat16(y);
            }
        }
    }
}

// ---------------------------------------------------------------------------
extern "C" void kernel_launch(void* const* d_in, const int* in_sizes, int n_in,
                              void* d_out, int out_size, void* d_ws, size_t ws_size,
                              hipStream_t stream)
{
    const float* x         = (const float*)d_in[0];
    const float* in_proj_w = (const float*)d_in[1];
    const float* conv_w    = (const float*)d_in[2];
    const float* conv_b    = (const float*)d_in[3];
    const float* x_proj_w  = (const float*)d_in[4];
    const float* dt_proj_w = (const float*)d_in[5];
    const float* dt_proj_b = (const float*)d_in[6];
    const float* A_log     = (const float*)d_in[7];
    const float* Dvec      = (const float*)d_in[8];
    const float* out_proj_w= (const float*)d_in[9];

    // workspace (all transposed [d][ml] bf16 except x_dbl): ~26.1 MB
    bf16* xp_raw_t = (bf16*)d_ws;                        // [768][ML] (reused as y_t)
    bf16* zs_t     = xp_raw_t + (size_t)ML * D_INNER;    // [768][ML] silu(z)
    bf16* xp_t     = zs_t     + (size_t)ML * D_INNER;    // [768][ML]
    bf16* dt_t     = xp_t     + (size_t)ML * D_INNER;    // [768][ML]
    float* x_dbl   = (float*)(dt_t + (size_t)ML * D_INNER); // [ML][56] fp32
    bf16* y_t      = xp_raw_t;                           // alias (dead after conv)

    dim3 blk(256);

    // 1) in_proj (64x64, proven): -> xp_raw_t | zs_t (transposed)
    gemm_mfma<0, 0><<<dim3(2 * D_INNER / 64, ML / 64), blk, 0, stream>>>(
        x, nullptr, in_proj_w, xp_raw_t, zs_t, nullptr, ML, 2 * D_INNER, D_MODEL);

    // 2) depthwise causal conv + silu
    conv_silu_kernel<<<dim3(ML / 256, D_INNER), blk, 0, stream>>>(
        xp_raw_t, conv_w, conv_b, xp_t);

    // 3) x_proj, K-split x4 with fp32 atomics (x_dbl zeroed first)
    hipMemsetAsync(x_dbl, 0, (size_t)ML * 56 * sizeof(float), stream);
    gemm_xproj_split<<<dim3(4, ML / 64), blk, 0, stream>>>(
        xp_t, x_proj_w, x_dbl, ML, 56, D_INNER);

    // 4) dt_proj + softplus (LDS-tiled) -> dt_t
    dt_kernel<<<dim3(ML / 64, D_INNER / 48), blk, 0, stream>>>(
        x_dbl, dt_proj_w, dt_proj_b, dt_t);

    // 5) chunk-parallel selective scan -> y_t (aliases xp_raw_t)
    scan_kernel<<<B_SZ * D_INNER, 1024, 0, stream>>>(
        dt_t, xp_t, x_dbl, zs_t, A_log, Dvec, y_t);

    // 6) out_proj: A = y_t (transposed), W (768x384) -> d_out fp32
    gemm_mfma<1, 1><<<dim3(D_MODEL / 64, ML / 64), blk, 0, stream>>>(
        nullptr, y_t, out_proj_w, nullptr, nullptr, (float*)d_out, ML, D_MODEL, D_INNER);
}

// Round 21
// 252.740 us; speedup vs baseline: 1.0340x; 1.0245x over previous
//
#include <hip/hip_runtime.h>
#include <hip/hip_bf16.h>

#define B_SZ    2
#define L_SEQ   2048
#define D_MODEL 384
#define D_INNER 768
#define D_STATE 16
#define DT_RANK 24
#define ML      (B_SZ * L_SEQ)   // 4096 rows
#define NCHUNK  64
#define CHLEN   (L_SEQ / NCHUNK) // 32

typedef __hip_bfloat16 bf16;
typedef __attribute__((ext_vector_type(8))) short bf16x8;
typedef __attribute__((ext_vector_type(4))) float f32x4;
typedef __attribute__((ext_vector_type(8))) float f32x8;

// ---------------------------------------------------------------------------
// MFMA bf16 GEMM (R12/R14/R16-verbatim, green). C(MxN) = A(MxK) * W(KxN).
// AMODE 0: A fp32 row-major [M][K] (in_proj).  AMODE 1: A bf16 transposed [K][M].
// 256 thr / 4 waves; tile 64x64, BK=64; wave = 32x32 via 2x2 16x16x32 MFMA.
// EPI 0: in_proj split, transposed: outb0[n][m]=xp_raw, outb1[n-768][m]=silu(z)
// EPI 1: outf = fp32 C row-major (ld=N, guard n<N)
// ---------------------------------------------------------------------------
template<int EPI, int AMODE>
__global__ __launch_bounds__(256)
void gemm_mfma(const float* __restrict__ Af, const bf16* __restrict__ At,
               const float* __restrict__ W,
               bf16* __restrict__ outb0, bf16* __restrict__ outb1,
               float* __restrict__ outf, int M, int N, int K)
{
    __shared__ __attribute__((aligned(16))) short As[64][72];
    __shared__ __attribute__((aligned(16))) short Bs[64][72];
    const int tid  = threadIdx.x;
    const int lane = tid & 63;
    const int wave = tid >> 6;
    const int wm   = (wave & 1) * 32;
    const int wn   = (wave >> 1) * 32;
    const int m0   = blockIdx.y * 64;
    const int n0   = blockIdx.x * 64;

    f32x4 acc[2][2];
#pragma unroll
    for (int i = 0; i < 2; i++)
#pragma unroll
        for (int j = 0; j < 2; j++)
#pragma unroll
            for (int r = 0; r < 4; r++) acc[i][j][r] = 0.f;

    for (int kt = 0; kt < K; kt += 64) {
        __syncthreads();
        // Stage A tile 64x64
#pragma unroll
        for (int i = 0; i < 2; i++) {
            int c = tid + 256 * i;
            if (AMODE == 0) {                    // fp32 row-major
                int m = c >> 3, k8 = (c & 7) * 8;
                f32x8 a = *(const f32x8*)&Af[(size_t)(m0 + m) * K + kt + k8];
                bf16x8 h;
#pragma unroll
                for (int j = 0; j < 8; j++)
                    h[j] = (short)__bfloat16_as_ushort(__float2bfloat16(a[j]));
                *(bf16x8*)&As[m][k8] = h;
            } else {                             // bf16 transposed [K][M]
                int m8 = (c & 7) * 8, k = c >> 3;
                bf16x8 a = *(const bf16x8*)&At[(size_t)(kt + k) * M + m0 + m8];
#pragma unroll
                for (int j = 0; j < 8; j++) As[m8 + j][k] = a[j];
            }
        }
        // Stage W tile 64x64 transposed into Bs[n][k], fp32 -> bf16
#pragma unroll
        for (int i = 0; i < 2; i++) {
            int c = tid + 256 * i;
            int n8 = (c & 7) * 8, k = c >> 3;
            if (n0 + n8 + 8 <= N) {
                f32x8 w = *(const f32x8*)&W[(size_t)(kt + k) * N + n0 + n8];
#pragma unroll
                for (int j = 0; j < 8; j++)
                    Bs[n8 + j][k] = (short)__bfloat16_as_ushort(__float2bfloat16(w[j]));
            } else {
#pragma unroll
                for (int j = 0; j < 8; j++) Bs[n8 + j][k] = 0;
            }
        }
        __syncthreads();
#pragma unroll
        for (int ks = 0; ks < 2; ks++) {
            int kb = ks * 32 + (lane >> 4) * 8;
            bf16x8 a0 = *(const bf16x8*)&As[wm + (lane & 15)][kb];
            bf16x8 a1 = *(const bf16x8*)&As[wm + 16 + (lane & 15)][kb];
            bf16x8 b0 = *(const bf16x8*)&Bs[wn + (lane & 15)][kb];
            bf16x8 b1 = *(const bf16x8*)&Bs[wn + 16 + (lane & 15)][kb];
            acc[0][0] = __builtin_amdgcn_mfma_f32_16x16x32_bf16(a0, b0, acc[0][0], 0, 0, 0);
            acc[0][1] = __builtin_amdgcn_mfma_f32_16x16x32_bf16(a0, b1, acc[0][1], 0, 0, 0);
            acc[1][0] = __builtin_amdgcn_mfma_f32_16x16x32_bf16(a1, b0, acc[1][0], 0, 0, 0);
            acc[1][1] = __builtin_amdgcn_mfma_f32_16x16x32_bf16(a1, b1, acc[1][1], 0, 0, 0);
        }
    }

#pragma unroll
    for (int am = 0; am < 2; am++)
#pragma unroll
        for (int bn = 0; bn < 2; bn++)
#pragma unroll
            for (int r = 0; r < 4; r++) {
                int m = m0 + wm + am * 16 + (lane >> 4) * 4 + r;
                int n = n0 + wn + bn * 16 + (lane & 15);
                float v = acc[am][bn][r];
                if (EPI == 0) {
                    if (n < D_INNER)
                        outb0[(size_t)n * ML + m] = __float2bfloat16(v);
                    else
                        outb1[(size_t)(n - D_INNER) * ML + m] =
                            __float2bfloat16(v / (1.f + __expf(-v)));
                } else {
                    if (n < N) outf[(size_t)m * N + n] = v;
                }
            }
}

// ---------------------------------------------------------------------------
// x_proj GEMM with K-split x4 (R14/R16-verbatim, green): grid (4, ML/64).
// Partial over K in [kc*192, kc*192+192), atomicAdd fp32 into x_dbl.
// ---------------------------------------------------------------------------
__global__ __launch_bounds__(256)
void gemm_xproj_split(const bf16* __restrict__ At, const float* __restrict__ W,
                      float* __restrict__ outf, int M, int N, int K)
{
    __shared__ __attribute__((aligned(16))) short As[64][72];
    __shared__ __attribute__((aligned(16))) short Bs[64][72];
    const int tid  = threadIdx.x;
    const int lane = tid & 63;
    const int wave = tid >> 6;
    const int wm   = (wave & 1) * 32;
    const int wn   = (wave >> 1) * 32;
    const int m0   = blockIdx.y * 64;
    const int k0   = blockIdx.x * (768 / 4);     // 192-wide K chunk

    f32x4 acc[2][2];
#pragma unroll
    for (int i = 0; i < 2; i++)
#pragma unroll
        for (int j = 0; j < 2; j++)
#pragma unroll
            for (int r = 0; r < 4; r++) acc[i][j][r] = 0.f;

    for (int kt = k0; kt < k0 + 192; kt += 64) {
        __syncthreads();
#pragma unroll
        for (int i = 0; i < 2; i++) {
            int c = tid + 256 * i;
            int m8 = (c & 7) * 8, k = c >> 3;
            bf16x8 a = *(const bf16x8*)&At[(size_t)(kt + k) * M + m0 + m8];
#pragma unroll
            for (int j = 0; j < 8; j++) As[m8 + j][k] = a[j];
        }
#pragma unroll
        for (int i = 0; i < 2; i++) {
            int c = tid + 256 * i;
            int n8 = (c & 7) * 8, k = c >> 3;
            if (n8 + 8 <= N) {
                f32x8 w = *(const f32x8*)&W[(size_t)(kt + k) * N + n8];
#pragma unroll
                for (int j = 0; j < 8; j++)
                    Bs[n8 + j][k] = (short)__bfloat16_as_ushort(__float2bfloat16(w[j]));
            } else {
#pragma unroll
                for (int j = 0; j < 8; j++) Bs[n8 + j][k] = 0;
            }
        }
        __syncthreads();
#pragma unroll
        for (int ks = 0; ks < 2; ks++) {
            int kb = ks * 32 + (lane >> 4) * 8;
            bf16x8 a0 = *(const bf16x8*)&As[wm + (lane & 15)][kb];
            bf16x8 a1 = *(const bf16x8*)&As[wm + 16 + (lane & 15)][kb];
            bf16x8 b0 = *(const bf16x8*)&Bs[wn + (lane & 15)][kb];
            bf16x8 b1 = *(const bf16x8*)&Bs[wn + 16 + (lane & 15)][kb];
            acc[0][0] = __builtin_amdgcn_mfma_f32_16x16x32_bf16(a0, b0, acc[0][0], 0, 0, 0);
            acc[0][1] = __builtin_amdgcn_mfma_f32_16x16x32_bf16(a0, b1, acc[0][1], 0, 0, 0);
            acc[1][0] = __builtin_amdgcn_mfma_f32_16x16x32_bf16(a1, b0, acc[1][0], 0, 0, 0);
            acc[1][1] = __builtin_amdgcn_mfma_f32_16x16x32_bf16(a1, b1, acc[1][1], 0, 0, 0);
        }
    }

#pragma unroll
    for (int am = 0; am < 2; am++)
#pragma unroll
        for (int bn = 0; bn < 2; bn++)
#pragma unroll
            for (int r = 0; r < 4; r++) {
                int m = m0 + wm + am * 16 + (lane >> 4) * 4 + r;
                int n = wn + bn * 16 + (lane & 15);
                if (n < N)
                    atomicAdd(&outf[(size_t)m * N + n], acc[am][bn][r]);
            }
}

// ---------------------------------------------------------------------------
// Causal depthwise conv (K=4) + bias + SiLU on [d][ml]. (R12/R16-verbatim)
// ---------------------------------------------------------------------------
__global__ __launch_bounds__(256)
void conv_silu_kernel(const bf16* __restrict__ xp_raw_t,
                      const float* __restrict__ cw, const float* __restrict__ cb,
                      bf16* __restrict__ xp_t)
{
    const int ml = blockIdx.x * 256 + threadIdx.x;
    const int d  = blockIdx.y;
    const int l  = ml & (L_SEQ - 1);
    const size_t row = (size_t)d * ML;
    float s = cb[d];
#pragma unroll
    for (int j = 0; j < 4; j++) {
        if (l - 3 + j >= 0)
            s += __bfloat162float(xp_raw_t[row + ml - 3 + j]) * cw[d * 4 + j];
    }
    float act = s / (1.f + __expf(-s));                 // silu
    xp_t[row + ml] = __float2bfloat16(act);
}

// ---------------------------------------------------------------------------
// dt = softplus(dt_r @ dt_proj_w + b), LDS-tiled (R13/R16-verbatim): 64m x 48d.
// ---------------------------------------------------------------------------
__global__ __launch_bounds__(256)
void dt_kernel(const float* __restrict__ x_dbl, const float* __restrict__ dtw,
               const float* __restrict__ dtb, bf16* __restrict__ dt_t)
{
    __shared__ float xs[64 * 25];
    __shared__ float ws[24 * 48];
    const int tid = threadIdx.x;
    const int m0 = blockIdx.x * 64;
    const int d0 = blockIdx.y * 48;
#pragma unroll
    for (int i = 0; i < 6; i++) {
        int idx = tid + 256 * i;        // < 1536 = 64*24
        int r_ = idx / 24, cc = idx % 24;
        xs[r_ * 25 + cc] = x_dbl[(size_t)(m0 + r_) * 56 + cc];
    }
#pragma unroll
    for (int i = 0; i < 5; i++) {
        int idx = tid + 256 * i;
        if (idx < 24 * 48) {
            int r_ = idx / 48, dd = idx % 48;
            ws[idx] = dtw[r_ * D_INNER + d0 + dd];
        }
    }
    __syncthreads();
#pragma unroll
    for (int i = 0; i < 12; i++) {
        int o = tid + 256 * i;          // < 3072 = 64*48
        int mloc = o & 63, dd = o >> 6; // dd wave-uniform
        float acc = dtb[d0 + dd];
#pragma unroll
        for (int r_ = 0; r_ < 24; r_++)
            acc += xs[mloc * 25 + r_] * ws[r_ * 48 + dd];
        float sp = fmaxf(acc, 0.f) + log1pf(__expf(-fabsf(acc)));
        dt_t[(size_t)(d0 + dd) * ML + m0 + mloc] = __float2bfloat16(sp);
    }
}

// ---------------------------------------------------------------------------
// Chunk-parallel selective scan. R16-green structure (bf16x8 group loads,
// Kogge-Stone over chunks, butterfly reduce). ONLY change vs R16/R20:
// phase-3 epilogue select-latch — after the butterfly every lane holds the
// full 16-lane sum, so lane n latches (yv, xpv) at unrolled step k==n (two
// cndmask selects, compile-time k) and each 16-step group ends with ONE zs
// load + ONE contiguous 2B store per lane (32B/group coalesced), replacing
// 16 divergent lane-0 load/store iterations per group.
// ---------------------------------------------------------------------------
__global__ __launch_bounds__(1024)
void scan_kernel(const bf16* __restrict__ dt_t, const bf16* __restrict__ xp_t,
                 const float* __restrict__ x_dbl, const bf16* __restrict__ zs_t,
                 const float* __restrict__ A_log, const float* __restrict__ Dp,
                 bf16* __restrict__ y_t)
{
    __shared__ float sP[NCHUNK][D_STATE];
    __shared__ float sH[NCHUNK][D_STATE];
    const int tid = threadIdx.x;
    const int c = tid >> 4;           // chunk 0..63
    const int n = tid & 15;           // state 0..15
    const int g = blockIdx.x;         // (b,d)
    const int b = g / D_INNER;
    const int d = g % D_INNER;
    const float A = -__expf(A_log[d * D_STATE + n]);
    const size_t base_t = (size_t)d * ML + (size_t)b * L_SEQ + (size_t)c * CHLEN;
    const size_t base_m = (size_t)b * L_SEQ + (size_t)c * CHLEN;

    float h = 0.f, P = 1.f;
#pragma unroll
    for (int g2 = 0; g2 < 2; g2++) {
        bf16x8 vdt0 = *(const bf16x8*)&dt_t[base_t + g2 * 16];
        bf16x8 vdt1 = *(const bf16x8*)&dt_t[base_t + g2 * 16 + 8];
        bf16x8 vxp0 = *(const bf16x8*)&xp_t[base_t + g2 * 16];
        bf16x8 vxp1 = *(const bf16x8*)&xp_t[base_t + g2 * 16 + 8];
#pragma unroll
        for (int k = 0; k < 16; k++) {
            const int j = g2 * 16 + k;
            short sdt = (k < 8) ? vdt0[k & 7] : vdt1[k & 7];
            short sxp = (k < 8) ? vxp0[k & 7] : vxp1[k & 7];
            float dtv = __uint_as_float(((unsigned)(unsigned short)sdt) << 16);
            float xpv = __uint_as_float(((unsigned)(unsigned short)sxp) << 16);
            float Bn  = x_dbl[(base_m + j) * 56 + DT_RANK + n];
            float aj = __expf(dtv * A);
            h = aj * h + Bn * (dtv * xpv);
            P *= aj;
        }
    }
    sP[c][n] = P;
    sH[c][n] = h;
    __syncthreads();

    // Kogge-Stone inclusive scan over chunks: compose (P,h) pairs
#pragma unroll
    for (int s = 1; s < NCHUNK; s <<= 1) {
        float p2 = 0.f, h2 = 0.f;
        const bool act = (c >= s);
        if (act) { p2 = sP[c - s][n]; h2 = sH[c - s][n]; }
        __syncthreads();
        if (act) {
            sH[c][n] = sP[c][n] * h2 + sH[c][n];
            sP[c][n] = sP[c][n] * p2;
        }
        __syncthreads();
    }
    const float hinit = (c == 0) ? 0.f : sH[c - 1][n];

    // Phase 3: corrected re-scan + butterfly reduce + select-latch store
    const float Dd = Dp[d];
    h = hinit;
#pragma unroll
    for (int g2 = 0; g2 < 2; g2++) {
        bf16x8 vdt0 = *(const bf16x8*)&dt_t[base_t + g2 * 16];
        bf16x8 vdt1 = *(const bf16x8*)&dt_t[base_t + g2 * 16 + 8];
        bf16x8 vxp0 = *(const bf16x8*)&xp_t[base_t + g2 * 16];
        bf16x8 vxp1 = *(const bf16x8*)&xp_t[base_t + g2 * 16 + 8];
        float ymine = 0.f, xmine = 0.f;
#pragma unroll
        for (int k = 0; k < 16; k++) {
            const int j = g2 * 16 + k;
            short sdt = (k < 8) ? vdt0[k & 7] : vdt1[k & 7];
            short sxp = (k < 8) ? vxp0[k & 7] : vxp1[k & 7];
            float dtv = __uint_as_float(((unsigned)(unsigned short)sdt) << 16);
            float xpv = __uint_as_float(((unsigned)(unsigned short)sxp) << 16);
            float Bn  = x_dbl[(base_m + j) * 56 + DT_RANK + n];
            float aj = __expf(dtv * A);
            h = aj * h + Bn * (dtv * xpv);
            float Cn = x_dbl[(base_m + j) * 56 + DT_RANK + D_STATE + n];
            float yv = h * Cn;
            yv += __shfl_xor(yv, 1);
            yv += __shfl_xor(yv, 2);
            yv += __shfl_xor(yv, 4);
            yv += __shfl_xor(yv, 8);
            // all 16 lanes hold the full sum; lane n keeps step g2*16+n
            ymine = (k == n) ? yv : ymine;
            xmine = (k == n) ? xpv : xmine;
        }
        const int j = g2 * 16 + n;
        float zsv = __bfloat162float(zs_t[base_t + j]);
        y_t[base_t + j] = __float2bfloat16((ymine + xmine * Dd) * zsv);
    }
}

// ---------------------------------------------------------------------------
extern "C" void kernel_launch(void* const* d_in, const int* in_sizes, int n_in,
                              void* d_out, int out_size, void* d_ws, size_t ws_size,
                              hipStream_t stream)
{
    const float* x         = (const float*)d_in[0];
    const float* in_proj_w = (const float*)d_in[1];
    const float* conv_w    = (const float*)d_in[2];
    const float* conv_b    = (const float*)d_in[3];
    const float* x_proj_w  = (const float*)d_in[4];
    const float* dt_proj_w = (const float*)d_in[5];
    const float* dt_proj_b = (const float*)d_in[6];
    const float* A_log     = (const float*)d_in[7];
    const float* Dvec      = (const float*)d_in[8];
    const float* out_proj_w= (const float*)d_in[9];

    // workspace (all transposed [d][ml] bf16 except x_dbl): ~26.1 MB
    bf16* xp_raw_t = (bf16*)d_ws;                        // [768][ML] (reused as y_t)
    bf16* zs_t     = xp_raw_t + (size_t)ML * D_INNER;    // [768][ML] silu(z)
    bf16* xp_t     = zs_t     + (size_t)ML * D_INNER;    // [768][ML]
    bf16* dt_t     = xp_t     + (size_t)ML * D_INNER;    // [768][ML]
    float* x_dbl   = (float*)(dt_t + (size_t)ML * D_INNER); // [ML][56] fp32
    bf16* y_t      = xp_raw_t;                           // alias (dead after conv)

    dim3 blk(256);

    // 1) in_proj (64x64, proven): -> xp_raw_t | zs_t (transposed)
    gemm_mfma<0, 0><<<dim3(2 * D_INNER / 64, ML / 64), blk, 0, stream>>>(
        x, nullptr, in_proj_w, xp_raw_t, zs_t, nullptr, ML, 2 * D_INNER, D_MODEL);

    // 2) depthwise causal conv + silu
    conv_silu_kernel<<<dim3(ML / 256, D_INNER), blk, 0, stream>>>(
        xp_raw_t, conv_w, conv_b, xp_t);

    // 3) x_proj, K-split x4 with fp32 atomics (x_dbl zeroed first)
    hipMemsetAsync(x_dbl, 0, (size_t)ML * 56 * sizeof(float), stream);
    gemm_xproj_split<<<dim3(4, ML / 64), blk, 0, stream>>>(
        xp_t, x_proj_w, x_dbl, ML, 56, D_INNER);

    // 4) dt_proj + softplus (LDS-tiled) -> dt_t
    dt_kernel<<<dim3(ML / 64, D_INNER / 48), blk, 0, stream>>>(
        x_dbl, dt_proj_w, dt_proj_b, dt_t);

    // 5) chunk-parallel selective scan -> y_t (aliases xp_raw_t)
    scan_kernel<<<B_SZ * D_INNER, 1024, 0, stream>>>(
        dt_t, xp_t, x_dbl, zs_t, A_log, Dvec, y_t);

    // 6) out_proj: A = y_t (transposed), W (768x384) -> d_out fp32
    gemm_mfma<1, 1><<<dim3(D_MODEL / 64, ML / 64), blk, 0, stream>>>(
        nullptr, y_t, out_proj_w, nullptr, nullptr, (float*)d_out, ML, D_MODEL, D_INNER);
}

// Round 22
// 247.922 us; speedup vs baseline: 1.0541x; 1.0194x over previous
//
#include <hip/hip_runtime.h>
#include <hip/hip_bf16.h>

#define B_SZ    2
#define L_SEQ   2048
#define D_MODEL 384
#define D_INNER 768
#define D_STATE 16
#define DT_RANK 24
#define ML      (B_SZ * L_SEQ)   // 4096 rows
#define NCHUNK  64
#define CHLEN   (L_SEQ / NCHUNK) // 32

typedef __hip_bfloat16 bf16;
typedef __attribute__((ext_vector_type(8))) short bf16x8;
typedef __attribute__((ext_vector_type(4))) float f32x4;
typedef __attribute__((ext_vector_type(8))) float f32x8;

// ---------------------------------------------------------------------------
// MFMA bf16 GEMM (R12/R14/R16-verbatim, green). C(MxN) = A(MxK) * W(KxN).
// AMODE 0: A fp32 row-major [M][K] (in_proj).  AMODE 1: A bf16 transposed [K][M].
// 256 thr / 4 waves; tile 64x64, BK=64; wave = 32x32 via 2x2 16x16x32 MFMA.
// EPI 0: in_proj split, transposed: outb0[n][m]=xp_raw, outb1[n-768][m]=silu(z)
// EPI 1: outf = fp32 C row-major (ld=N, guard n<N)
// ---------------------------------------------------------------------------
template<int EPI, int AMODE>
__global__ __launch_bounds__(256)
void gemm_mfma(const float* __restrict__ Af, const bf16* __restrict__ At,
               const float* __restrict__ W,
               bf16* __restrict__ outb0, bf16* __restrict__ outb1,
               float* __restrict__ outf, int M, int N, int K)
{
    __shared__ __attribute__((aligned(16))) short As[64][72];
    __shared__ __attribute__((aligned(16))) short Bs[64][72];
    const int tid  = threadIdx.x;
    const int lane = tid & 63;
    const int wave = tid >> 6;
    const int wm   = (wave & 1) * 32;
    const int wn   = (wave >> 1) * 32;
    const int m0   = blockIdx.y * 64;
    const int n0   = blockIdx.x * 64;

    f32x4 acc[2][2];
#pragma unroll
    for (int i = 0; i < 2; i++)
#pragma unroll
        for (int j = 0; j < 2; j++)
#pragma unroll
            for (int r = 0; r < 4; r++) acc[i][j][r] = 0.f;

    for (int kt = 0; kt < K; kt += 64) {
        __syncthreads();
        // Stage A tile 64x64
#pragma unroll
        for (int i = 0; i < 2; i++) {
            int c = tid + 256 * i;
            if (AMODE == 0) {                    // fp32 row-major
                int m = c >> 3, k8 = (c & 7) * 8;
                f32x8 a = *(const f32x8*)&Af[(size_t)(m0 + m) * K + kt + k8];
                bf16x8 h;
#pragma unroll
                for (int j = 0; j < 8; j++)
                    h[j] = (short)__bfloat16_as_ushort(__float2bfloat16(a[j]));
                *(bf16x8*)&As[m][k8] = h;
            } else {                             // bf16 transposed [K][M]
                int m8 = (c & 7) * 8, k = c >> 3;
                bf16x8 a = *(const bf16x8*)&At[(size_t)(kt + k) * M + m0 + m8];
#pragma unroll
                for (int j = 0; j < 8; j++) As[m8 + j][k] = a[j];
            }
        }
        // Stage W tile 64x64 transposed into Bs[n][k], fp32 -> bf16
#pragma unroll
        for (int i = 0; i < 2; i++) {
            int c = tid + 256 * i;
            int n8 = (c & 7) * 8, k = c >> 3;
            if (n0 + n8 + 8 <= N) {
                f32x8 w = *(const f32x8*)&W[(size_t)(kt + k) * N + n0 + n8];
#pragma unroll
                for (int j = 0; j < 8; j++)
                    Bs[n8 + j][k] = (short)__bfloat16_as_ushort(__float2bfloat16(w[j]));
            } else {
#pragma unroll
                for (int j = 0; j < 8; j++) Bs[n8 + j][k] = 0;
            }
        }
        __syncthreads();
#pragma unroll
        for (int ks = 0; ks < 2; ks++) {
            int kb = ks * 32 + (lane >> 4) * 8;
            bf16x8 a0 = *(const bf16x8*)&As[wm + (lane & 15)][kb];
            bf16x8 a1 = *(const bf16x8*)&As[wm + 16 + (lane & 15)][kb];
            bf16x8 b0 = *(const bf16x8*)&Bs[wn + (lane & 15)][kb];
            bf16x8 b1 = *(const bf16x8*)&Bs[wn + 16 + (lane & 15)][kb];
            acc[0][0] = __builtin_amdgcn_mfma_f32_16x16x32_bf16(a0, b0, acc[0][0], 0, 0, 0);
            acc[0][1] = __builtin_amdgcn_mfma_f32_16x16x32_bf16(a0, b1, acc[0][1], 0, 0, 0);
            acc[1][0] = __builtin_amdgcn_mfma_f32_16x16x32_bf16(a1, b0, acc[1][0], 0, 0, 0);
            acc[1][1] = __builtin_amdgcn_mfma_f32_16x16x32_bf16(a1, b1, acc[1][1], 0, 0, 0);
        }
    }

#pragma unroll
    for (int am = 0; am < 2; am++)
#pragma unroll
        for (int bn = 0; bn < 2; bn++)
#pragma unroll
            for (int r = 0; r < 4; r++) {
                int m = m0 + wm + am * 16 + (lane >> 4) * 4 + r;
                int n = n0 + wn + bn * 16 + (lane & 15);
                float v = acc[am][bn][r];
                if (EPI == 0) {
                    if (n < D_INNER)
                        outb0[(size_t)n * ML + m] = __float2bfloat16(v);
                    else
                        outb1[(size_t)(n - D_INNER) * ML + m] =
                            __float2bfloat16(v / (1.f + __expf(-v)));
                } else {
                    if (n < N) outf[(size_t)m * N + n] = v;
                }
            }
}

// ---------------------------------------------------------------------------
// x_proj GEMM with K-split x4 (R14/R16-verbatim, green): grid (4, ML/64).
// Partial over K in [kc*192, kc*192+192), atomicAdd fp32 into x_dbl.
// ---------------------------------------------------------------------------
__global__ __launch_bounds__(256)
void gemm_xproj_split(const bf16* __restrict__ At, const float* __restrict__ W,
                      float* __restrict__ outf, int M, int N, int K)
{
    __shared__ __attribute__((aligned(16))) short As[64][72];
    __shared__ __attribute__((aligned(16))) short Bs[64][72];
    const int tid  = threadIdx.x;
    const int lane = tid & 63;
    const int wave = tid >> 6;
    const int wm   = (wave & 1) * 32;
    const int wn   = (wave >> 1) * 32;
    const int m0   = blockIdx.y * 64;
    const int k0   = blockIdx.x * (768 / 4);     // 192-wide K chunk

    f32x4 acc[2][2];
#pragma unroll
    for (int i = 0; i < 2; i++)
#pragma unroll
        for (int j = 0; j < 2; j++)
#pragma unroll
            for (int r = 0; r < 4; r++) acc[i][j][r] = 0.f;

    for (int kt = k0; kt < k0 + 192; kt += 64) {
        __syncthreads();
#pragma unroll
        for (int i = 0; i < 2; i++) {
            int c = tid + 256 * i;
            int m8 = (c & 7) * 8, k = c >> 3;
            bf16x8 a = *(const bf16x8*)&At[(size_t)(kt + k) * M + m0 + m8];
#pragma unroll
            for (int j = 0; j < 8; j++) As[m8 + j][k] = a[j];
        }
#pragma unroll
        for (int i = 0; i < 2; i++) {
            int c = tid + 256 * i;
            int n8 = (c & 7) * 8, k = c >> 3;
            if (n8 + 8 <= N) {
                f32x8 w = *(const f32x8*)&W[(size_t)(kt + k) * N + n8];
#pragma unroll
                for (int j = 0; j < 8; j++)
                    Bs[n8 + j][k] = (short)__bfloat16_as_ushort(__float2bfloat16(w[j]));
            } else {
#pragma unroll
                for (int j = 0; j < 8; j++) Bs[n8 + j][k] = 0;
            }
        }
        __syncthreads();
#pragma unroll
        for (int ks = 0; ks < 2; ks++) {
            int kb = ks * 32 + (lane >> 4) * 8;
            bf16x8 a0 = *(const bf16x8*)&As[wm + (lane & 15)][kb];
            bf16x8 a1 = *(const bf16x8*)&As[wm + 16 + (lane & 15)][kb];
            bf16x8 b0 = *(const bf16x8*)&Bs[wn + (lane & 15)][kb];
            bf16x8 b1 = *(const bf16x8*)&Bs[wn + 16 + (lane & 15)][kb];
            acc[0][0] = __builtin_amdgcn_mfma_f32_16x16x32_bf16(a0, b0, acc[0][0], 0, 0, 0);
            acc[0][1] = __builtin_amdgcn_mfma_f32_16x16x32_bf16(a0, b1, acc[0][1], 0, 0, 0);
            acc[1][0] = __builtin_amdgcn_mfma_f32_16x16x32_bf16(a1, b0, acc[1][0], 0, 0, 0);
            acc[1][1] = __builtin_amdgcn_mfma_f32_16x16x32_bf16(a1, b1, acc[1][1], 0, 0, 0);
        }
    }

#pragma unroll
    for (int am = 0; am < 2; am++)
#pragma unroll
        for (int bn = 0; bn < 2; bn++)
#pragma unroll
            for (int r = 0; r < 4; r++) {
                int m = m0 + wm + am * 16 + (lane >> 4) * 4 + r;
                int n = wn + bn * 16 + (lane & 15);
                if (n < N)
                    atomicAdd(&outf[(size_t)m * N + n], acc[am][bn][r]);
            }
}

// ---------------------------------------------------------------------------
// Causal depthwise conv (K=4) + bias + SiLU, 8 outputs/thread (R8-green
// structure), [d][ml] layout. grid = (ML/2048, D_INNER), block 256.
// Each thread: 2x bf16x8 window loads + 1x bf16x8 store (vs 4 scalar loads
// + 1 scalar store per output in the R21 scalar version).
// ---------------------------------------------------------------------------
__global__ __launch_bounds__(256)
void conv_silu_kernel(const bf16* __restrict__ xp_raw_t,
                      const float* __restrict__ cw, const float* __restrict__ cb,
                      bf16* __restrict__ xp_t)
{
    const int ml0 = (blockIdx.x * 256 + threadIdx.x) * 8;
    const int d   = blockIdx.y;
    const int l0  = ml0 & (L_SEQ - 1);           // 8-aligned; l0+7 < L_SEQ
    const size_t row = (size_t)d * ML;
    const float w0 = cw[d * 4 + 0], w1 = cw[d * 4 + 1],
                w2 = cw[d * 4 + 2], w3 = cw[d * 4 + 3], bias = cb[d];

    bf16x8 cur = *(const bf16x8*)&xp_raw_t[row + ml0];
    bf16x8 prev;
    if (ml0 != 0) prev = *(const bf16x8*)&xp_raw_t[row + ml0 - 8];
    else {
#pragma unroll
        for (int j = 0; j < 8; j++) prev[j] = 0;
    }
    float w[16];
#pragma unroll
    for (int k = 0; k < 8; k++) {
        w[k]     = __uint_as_float(((unsigned)(unsigned short)prev[k]) << 16);
        w[k + 8] = __uint_as_float(((unsigned)(unsigned short)cur[k]) << 16);
    }

    bf16x8 out;
#pragma unroll
    for (int o = 0; o < 8; o++) {
        int l = l0 + o;
        float s = bias;
        if (l >= 3) {
            s += w0 * w[5 + o] + w1 * w[6 + o] + w2 * w[7 + o] + w3 * w[8 + o];
        } else {
            if (l - 3 >= 0) s += w0 * w[5 + o];
            if (l - 2 >= 0) s += w1 * w[6 + o];
            if (l - 1 >= 0) s += w2 * w[7 + o];
            s += w3 * w[8 + o];
        }
        float act = s / (1.f + __expf(-s));
        out[o] = (short)__bfloat16_as_ushort(__float2bfloat16(act));
    }
    *(bf16x8*)&xp_t[row + ml0] = out;
}

// ---------------------------------------------------------------------------
// dt = softplus(dt_r @ dt_proj_w + b), LDS-tiled (R13/R16-verbatim): 64m x 48d.
// ---------------------------------------------------------------------------
__global__ __launch_bounds__(256)
void dt_kernel(const float* __restrict__ x_dbl, const float* __restrict__ dtw,
               const float* __restrict__ dtb, bf16* __restrict__ dt_t)
{
    __shared__ float xs[64 * 25];
    __shared__ float ws[24 * 48];
    const int tid = threadIdx.x;
    const int m0 = blockIdx.x * 64;
    const int d0 = blockIdx.y * 48;
#pragma unroll
    for (int i = 0; i < 6; i++) {
        int idx = tid + 256 * i;        // < 1536 = 64*24
        int r_ = idx / 24, cc = idx % 24;
        xs[r_ * 25 + cc] = x_dbl[(size_t)(m0 + r_) * 56 + cc];
    }
#pragma unroll
    for (int i = 0; i < 5; i++) {
        int idx = tid + 256 * i;
        if (idx < 24 * 48) {
            int r_ = idx / 48, dd = idx % 48;
            ws[idx] = dtw[r_ * D_INNER + d0 + dd];
        }
    }
    __syncthreads();
#pragma unroll
    for (int i = 0; i < 12; i++) {
        int o = tid + 256 * i;          // < 3072 = 64*48
        int mloc = o & 63, dd = o >> 6; // dd wave-uniform
        float acc = dtb[d0 + dd];
#pragma unroll
        for (int r_ = 0; r_ < 24; r_++)
            acc += xs[mloc * 25 + r_] * ws[r_ * 48 + dd];
        float sp = fmaxf(acc, 0.f) + log1pf(__expf(-fabsf(acc)));
        dt_t[(size_t)(d0 + dd) * ML + m0 + mloc] = __float2bfloat16(sp);
    }
}

// ---------------------------------------------------------------------------
// Chunk-parallel selective scan (R21-verbatim, green): bf16x8 group loads,
// Kogge-Stone over chunks, butterfly reduce, select-latch epilogue.
// ---------------------------------------------------------------------------
__global__ __launch_bounds__(1024)
void scan_kernel(const bf16* __restrict__ dt_t, const bf16* __restrict__ xp_t,
                 const float* __restrict__ x_dbl, const bf16* __restrict__ zs_t,
                 const float* __restrict__ A_log, const float* __restrict__ Dp,
                 bf16* __restrict__ y_t)
{
    __shared__ float sP[NCHUNK][D_STATE];
    __shared__ float sH[NCHUNK][D_STATE];
    const int tid = threadIdx.x;
    const int c = tid >> 4;           // chunk 0..63
    const int n = tid & 15;           // state 0..15
    const int g = blockIdx.x;         // (b,d)
    const int b = g / D_INNER;
    const int d = g % D_INNER;
    const float A = -__expf(A_log[d * D_STATE + n]);
    const size_t base_t = (size_t)d * ML + (size_t)b * L_SEQ + (size_t)c * CHLEN;
    const size_t base_m = (size_t)b * L_SEQ + (size_t)c * CHLEN;

    float h = 0.f, P = 1.f;
#pragma unroll
    for (int g2 = 0; g2 < 2; g2++) {
        bf16x8 vdt0 = *(const bf16x8*)&dt_t[base_t + g2 * 16];
        bf16x8 vdt1 = *(const bf16x8*)&dt_t[base_t + g2 * 16 + 8];
        bf16x8 vxp0 = *(const bf16x8*)&xp_t[base_t + g2 * 16];
        bf16x8 vxp1 = *(const bf16x8*)&xp_t[base_t + g2 * 16 + 8];
#pragma unroll
        for (int k = 0; k < 16; k++) {
            const int j = g2 * 16 + k;
            short sdt = (k < 8) ? vdt0[k & 7] : vdt1[k & 7];
            short sxp = (k < 8) ? vxp0[k & 7] : vxp1[k & 7];
            float dtv = __uint_as_float(((unsigned)(unsigned short)sdt) << 16);
            float xpv = __uint_as_float(((unsigned)(unsigned short)sxp) << 16);
            float Bn  = x_dbl[(base_m + j) * 56 + DT_RANK + n];
            float aj = __expf(dtv * A);
            h = aj * h + Bn * (dtv * xpv);
            P *= aj;
        }
    }
    sP[c][n] = P;
    sH[c][n] = h;
    __syncthreads();

    // Kogge-Stone inclusive scan over chunks: compose (P,h) pairs
#pragma unroll
    for (int s = 1; s < NCHUNK; s <<= 1) {
        float p2 = 0.f, h2 = 0.f;
        const bool act = (c >= s);
        if (act) { p2 = sP[c - s][n]; h2 = sH[c - s][n]; }
        __syncthreads();
        if (act) {
            sH[c][n] = sP[c][n] * h2 + sH[c][n];
            sP[c][n] = sP[c][n] * p2;
        }
        __syncthreads();
    }
    const float hinit = (c == 0) ? 0.f : sH[c - 1][n];

    // Phase 3: corrected re-scan + butterfly reduce + select-latch store
    const float Dd = Dp[d];
    h = hinit;
#pragma unroll
    for (int g2 = 0; g2 < 2; g2++) {
        bf16x8 vdt0 = *(const bf16x8*)&dt_t[base_t + g2 * 16];
        bf16x8 vdt1 = *(const bf16x8*)&dt_t[base_t + g2 * 16 + 8];
        bf16x8 vxp0 = *(const bf16x8*)&xp_t[base_t + g2 * 16];
        bf16x8 vxp1 = *(const bf16x8*)&xp_t[base_t + g2 * 16 + 8];
        float ymine = 0.f, xmine = 0.f;
#pragma unroll
        for (int k = 0; k < 16; k++) {
            const int j = g2 * 16 + k;
            short sdt = (k < 8) ? vdt0[k & 7] : vdt1[k & 7];
            short sxp = (k < 8) ? vxp0[k & 7] : vxp1[k & 7];
            float dtv = __uint_as_float(((unsigned)(unsigned short)sdt) << 16);
            float xpv = __uint_as_float(((unsigned)(unsigned short)sxp) << 16);
            float Bn  = x_dbl[(base_m + j) * 56 + DT_RANK + n];
            float aj = __expf(dtv * A);
            h = aj * h + Bn * (dtv * xpv);
            float Cn = x_dbl[(base_m + j) * 56 + DT_RANK + D_STATE + n];
            float yv = h * Cn;
            yv += __shfl_xor(yv, 1);
            yv += __shfl_xor(yv, 2);
            yv += __shfl_xor(yv, 4);
            yv += __shfl_xor(yv, 8);
            // all 16 lanes hold the full sum; lane n keeps step g2*16+n
            ymine = (k == n) ? yv : ymine;
            xmine = (k == n) ? xpv : xmine;
        }
        const int j = g2 * 16 + n;
        float zsv = __bfloat162float(zs_t[base_t + j]);
        y_t[base_t + j] = __float2bfloat16((ymine + xmine * Dd) * zsv);
    }
}

// ---------------------------------------------------------------------------
extern "C" void kernel_launch(void* const* d_in, const int* in_sizes, int n_in,
                              void* d_out, int out_size, void* d_ws, size_t ws_size,
                              hipStream_t stream)
{
    const float* x         = (const float*)d_in[0];
    const float* in_proj_w = (const float*)d_in[1];
    const float* conv_w    = (const float*)d_in[2];
    const float* conv_b    = (const float*)d_in[3];
    const float* x_proj_w  = (const float*)d_in[4];
    const float* dt_proj_w = (const float*)d_in[5];
    const float* dt_proj_b = (const float*)d_in[6];
    const float* A_log     = (const float*)d_in[7];
    const float* Dvec      = (const float*)d_in[8];
    const float* out_proj_w= (const float*)d_in[9];

    // workspace (all transposed [d][ml] bf16 except x_dbl): ~26.1 MB
    bf16* xp_raw_t = (bf16*)d_ws;                        // [768][ML] (reused as y_t)
    bf16* zs_t     = xp_raw_t + (size_t)ML * D_INNER;    // [768][ML] silu(z)
    bf16* xp_t     = zs_t     + (size_t)ML * D_INNER;    // [768][ML]
    bf16* dt_t     = xp_t     + (size_t)ML * D_INNER;    // [768][ML]
    float* x_dbl   = (float*)(dt_t + (size_t)ML * D_INNER); // [ML][56] fp32
    bf16* y_t      = xp_raw_t;                           // alias (dead after conv)

    dim3 blk(256);

    // 1) in_proj (64x64, proven): -> xp_raw_t | zs_t (transposed)
    gemm_mfma<0, 0><<<dim3(2 * D_INNER / 64, ML / 64), blk, 0, stream>>>(
        x, nullptr, in_proj_w, xp_raw_t, zs_t, nullptr, ML, 2 * D_INNER, D_MODEL);

    // 2) depthwise causal conv + silu (8 outputs/thread)
    conv_silu_kernel<<<dim3(ML / 2048, D_INNER), blk, 0, stream>>>(
        xp_raw_t, conv_w, conv_b, xp_t);

    // 3) x_proj, K-split x4 with fp32 atomics (x_dbl zeroed first)
    hipMemsetAsync(x_dbl, 0, (size_t)ML * 56 * sizeof(float), stream);
    gemm_xproj_split<<<dim3(4, ML / 64), blk, 0, stream>>>(
        xp_t, x_proj_w, x_dbl, ML, 56, D_INNER);

    // 4) dt_proj + softplus (LDS-tiled) -> dt_t
    dt_kernel<<<dim3(ML / 64, D_INNER / 48), blk, 0, stream>>>(
        x_dbl, dt_proj_w, dt_proj_b, dt_t);

    // 5) chunk-parallel selective scan -> y_t (aliases xp_raw_t)
    scan_kernel<<<B_SZ * D_INNER, 1024, 0, stream>>>(
        dt_t, xp_t, x_dbl, zs_t, A_log, Dvec, y_t);

    // 6) out_proj: A = y_t (transposed), W (768x384) -> d_out fp32
    gemm_mfma<1, 1><<<dim3(D_MODEL / 64, ML / 64), blk, 0, stream>>>(
        nullptr, y_t, out_proj_w, nullptr, nullptr, (float*)d_out, ML, D_MODEL, D_INNER);
}

// Round 23
// 242.966 us; speedup vs baseline: 1.0756x; 1.0204x over previous
//
#include <hip/hip_runtime.h>
#include <hip/hip_bf16.h>

#define B_SZ    2
#define L_SEQ   2048
#define D_MODEL 384
#define D_INNER 768
#define D_STATE 16
#define DT_RANK 24
#define ML      (B_SZ * L_SEQ)   // 4096 rows
#define NCHUNK  64
#define CHLEN   (L_SEQ / NCHUNK) // 32

typedef __hip_bfloat16 bf16;
typedef __attribute__((ext_vector_type(8))) short bf16x8;
typedef __attribute__((ext_vector_type(4))) float f32x4;
typedef __attribute__((ext_vector_type(8))) float f32x8;

// ---------------------------------------------------------------------------
// MFMA bf16 GEMM (R12/R14/R16-verbatim, green). C(MxN) = A(MxK) * W(KxN).
// AMODE 0: A fp32 row-major [M][K] (in_proj).  AMODE 1: A bf16 transposed [K][M].
// 256 thr / 4 waves; tile 64x64, BK=64; wave = 32x32 via 2x2 16x16x32 MFMA.
// EPI 0: in_proj split, transposed: outb0[n][m]=xp_raw, outb1[n-768][m]=silu(z)
// EPI 1: outf = fp32 C row-major (ld=N, guard n<N)
// ---------------------------------------------------------------------------
template<int EPI, int AMODE>
__global__ __launch_bounds__(256)
void gemm_mfma(const float* __restrict__ Af, const bf16* __restrict__ At,
               const float* __restrict__ W,
               bf16* __restrict__ outb0, bf16* __restrict__ outb1,
               float* __restrict__ outf, int M, int N, int K)
{
    __shared__ __attribute__((aligned(16))) short As[64][72];
    __shared__ __attribute__((aligned(16))) short Bs[64][72];
    const int tid  = threadIdx.x;
    const int lane = tid & 63;
    const int wave = tid >> 6;
    const int wm   = (wave & 1) * 32;
    const int wn   = (wave >> 1) * 32;
    const int m0   = blockIdx.y * 64;
    const int n0   = blockIdx.x * 64;

    f32x4 acc[2][2];
#pragma unroll
    for (int i = 0; i < 2; i++)
#pragma unroll
        for (int j = 0; j < 2; j++)
#pragma unroll
            for (int r = 0; r < 4; r++) acc[i][j][r] = 0.f;

    for (int kt = 0; kt < K; kt += 64) {
        __syncthreads();
        // Stage A tile 64x64
#pragma unroll
        for (int i = 0; i < 2; i++) {
            int c = tid + 256 * i;
            if (AMODE == 0) {                    // fp32 row-major
                int m = c >> 3, k8 = (c & 7) * 8;
                f32x8 a = *(const f32x8*)&Af[(size_t)(m0 + m) * K + kt + k8];
                bf16x8 h;
#pragma unroll
                for (int j = 0; j < 8; j++)
                    h[j] = (short)__bfloat16_as_ushort(__float2bfloat16(a[j]));
                *(bf16x8*)&As[m][k8] = h;
            } else {                             // bf16 transposed [K][M]
                int m8 = (c & 7) * 8, k = c >> 3;
                bf16x8 a = *(const bf16x8*)&At[(size_t)(kt + k) * M + m0 + m8];
#pragma unroll
                for (int j = 0; j < 8; j++) As[m8 + j][k] = a[j];
            }
        }
        // Stage W tile 64x64 transposed into Bs[n][k], fp32 -> bf16
#pragma unroll
        for (int i = 0; i < 2; i++) {
            int c = tid + 256 * i;
            int n8 = (c & 7) * 8, k = c >> 3;
            if (n0 + n8 + 8 <= N) {
                f32x8 w = *(const f32x8*)&W[(size_t)(kt + k) * N + n0 + n8];
#pragma unroll
                for (int j = 0; j < 8; j++)
                    Bs[n8 + j][k] = (short)__bfloat16_as_ushort(__float2bfloat16(w[j]));
            } else {
#pragma unroll
                for (int j = 0; j < 8; j++) Bs[n8 + j][k] = 0;
            }
        }
        __syncthreads();
#pragma unroll
        for (int ks = 0; ks < 2; ks++) {
            int kb = ks * 32 + (lane >> 4) * 8;
            bf16x8 a0 = *(const bf16x8*)&As[wm + (lane & 15)][kb];
            bf16x8 a1 = *(const bf16x8*)&As[wm + 16 + (lane & 15)][kb];
            bf16x8 b0 = *(const bf16x8*)&Bs[wn + (lane & 15)][kb];
            bf16x8 b1 = *(const bf16x8*)&Bs[wn + 16 + (lane & 15)][kb];
            acc[0][0] = __builtin_amdgcn_mfma_f32_16x16x32_bf16(a0, b0, acc[0][0], 0, 0, 0);
            acc[0][1] = __builtin_amdgcn_mfma_f32_16x16x32_bf16(a0, b1, acc[0][1], 0, 0, 0);
            acc[1][0] = __builtin_amdgcn_mfma_f32_16x16x32_bf16(a1, b0, acc[1][0], 0, 0, 0);
            acc[1][1] = __builtin_amdgcn_mfma_f32_16x16x32_bf16(a1, b1, acc[1][1], 0, 0, 0);
        }
    }

#pragma unroll
    for (int am = 0; am < 2; am++)
#pragma unroll
        for (int bn = 0; bn < 2; bn++)
#pragma unroll
            for (int r = 0; r < 4; r++) {
                int m = m0 + wm + am * 16 + (lane >> 4) * 4 + r;
                int n = n0 + wn + bn * 16 + (lane & 15);
                float v = acc[am][bn][r];
                if (EPI == 0) {
                    if (n < D_INNER)
                        outb0[(size_t)n * ML + m] = __float2bfloat16(v);
                    else
                        outb1[(size_t)(n - D_INNER) * ML + m] =
                            __float2bfloat16(v / (1.f + __expf(-v)));
                } else {
                    if (n < N) outf[(size_t)m * N + n] = v;
                }
            }
}

// ---------------------------------------------------------------------------
// x_proj GEMM with K-split x4 (R14/R16-verbatim, green): grid (4, ML/64).
// Partial over K in [kc*192, kc*192+192), atomicAdd fp32 into x_dbl.
// ---------------------------------------------------------------------------
__global__ __launch_bounds__(256)
void gemm_xproj_split(const bf16* __restrict__ At, const float* __restrict__ W,
                      float* __restrict__ outf, int M, int N, int K)
{
    __shared__ __attribute__((aligned(16))) short As[64][72];
    __shared__ __attribute__((aligned(16))) short Bs[64][72];
    const int tid  = threadIdx.x;
    const int lane = tid & 63;
    const int wave = tid >> 6;
    const int wm   = (wave & 1) * 32;
    const int wn   = (wave >> 1) * 32;
    const int m0   = blockIdx.y * 64;
    const int k0   = blockIdx.x * (768 / 4);     // 192-wide K chunk

    f32x4 acc[2][2];
#pragma unroll
    for (int i = 0; i < 2; i++)
#pragma unroll
        for (int j = 0; j < 2; j++)
#pragma unroll
            for (int r = 0; r < 4; r++) acc[i][j][r] = 0.f;

    for (int kt = k0; kt < k0 + 192; kt += 64) {
        __syncthreads();
#pragma unroll
        for (int i = 0; i < 2; i++) {
            int c = tid + 256 * i;
            int m8 = (c & 7) * 8, k = c >> 3;
            bf16x8 a = *(const bf16x8*)&At[(size_t)(kt + k) * M + m0 + m8];
#pragma unroll
            for (int j = 0; j < 8; j++) As[m8 + j][k] = a[j];
        }
#pragma unroll
        for (int i = 0; i < 2; i++) {
            int c = tid + 256 * i;
            int n8 = (c & 7) * 8, k = c >> 3;
            if (n8 + 8 <= N) {
                f32x8 w = *(const f32x8*)&W[(size_t)(kt + k) * N + n8];
#pragma unroll
                for (int j = 0; j < 8; j++)
                    Bs[n8 + j][k] = (short)__bfloat16_as_ushort(__float2bfloat16(w[j]));
            } else {
#pragma unroll
                for (int j = 0; j < 8; j++) Bs[n8 + j][k] = 0;
            }
        }
        __syncthreads();
#pragma unroll
        for (int ks = 0; ks < 2; ks++) {
            int kb = ks * 32 + (lane >> 4) * 8;
            bf16x8 a0 = *(const bf16x8*)&As[wm + (lane & 15)][kb];
            bf16x8 a1 = *(const bf16x8*)&As[wm + 16 + (lane & 15)][kb];
            bf16x8 b0 = *(const bf16x8*)&Bs[wn + (lane & 15)][kb];
            bf16x8 b1 = *(const bf16x8*)&Bs[wn + 16 + (lane & 15)][kb];
            acc[0][0] = __builtin_amdgcn_mfma_f32_16x16x32_bf16(a0, b0, acc[0][0], 0, 0, 0);
            acc[0][1] = __builtin_amdgcn_mfma_f32_16x16x32_bf16(a0, b1, acc[0][1], 0, 0, 0);
            acc[1][0] = __builtin_amdgcn_mfma_f32_16x16x32_bf16(a1, b0, acc[1][0], 0, 0, 0);
            acc[1][1] = __builtin_amdgcn_mfma_f32_16x16x32_bf16(a1, b1, acc[1][1], 0, 0, 0);
        }
    }

#pragma unroll
    for (int am = 0; am < 2; am++)
#pragma unroll
        for (int bn = 0; bn < 2; bn++)
#pragma unroll
            for (int r = 0; r < 4; r++) {
                int m = m0 + wm + am * 16 + (lane >> 4) * 4 + r;
                int n = wn + bn * 16 + (lane & 15);
                if (n < N)
                    atomicAdd(&outf[(size_t)m * N + n], acc[am][bn][r]);
            }
}

// ---------------------------------------------------------------------------
// Causal depthwise conv (K=4) + bias + SiLU, 8 outputs/thread (R22-verbatim).
// ---------------------------------------------------------------------------
__global__ __launch_bounds__(256)
void conv_silu_kernel(const bf16* __restrict__ xp_raw_t,
                      const float* __restrict__ cw, const float* __restrict__ cb,
                      bf16* __restrict__ xp_t)
{
    const int ml0 = (blockIdx.x * 256 + threadIdx.x) * 8;
    const int d   = blockIdx.y;
    const int l0  = ml0 & (L_SEQ - 1);           // 8-aligned; l0+7 < L_SEQ
    const size_t row = (size_t)d * ML;
    const float w0 = cw[d * 4 + 0], w1 = cw[d * 4 + 1],
                w2 = cw[d * 4 + 2], w3 = cw[d * 4 + 3], bias = cb[d];

    bf16x8 cur = *(const bf16x8*)&xp_raw_t[row + ml0];
    bf16x8 prev;
    if (ml0 != 0) prev = *(const bf16x8*)&xp_raw_t[row + ml0 - 8];
    else {
#pragma unroll
        for (int j = 0; j < 8; j++) prev[j] = 0;
    }
    float w[16];
#pragma unroll
    for (int k = 0; k < 8; k++) {
        w[k]     = __uint_as_float(((unsigned)(unsigned short)prev[k]) << 16);
        w[k + 8] = __uint_as_float(((unsigned)(unsigned short)cur[k]) << 16);
    }

    bf16x8 out;
#pragma unroll
    for (int o = 0; o < 8; o++) {
        int l = l0 + o;
        float s = bias;
        if (l >= 3) {
            s += w0 * w[5 + o] + w1 * w[6 + o] + w2 * w[7 + o] + w3 * w[8 + o];
        } else {
            if (l - 3 >= 0) s += w0 * w[5 + o];
            if (l - 2 >= 0) s += w1 * w[6 + o];
            if (l - 1 >= 0) s += w2 * w[7 + o];
            s += w3 * w[8 + o];
        }
        float act = s / (1.f + __expf(-s));
        out[o] = (short)__bfloat16_as_ushort(__float2bfloat16(act));
    }
    *(bf16x8*)&xp_t[row + ml0] = out;
}

// ---------------------------------------------------------------------------
// dt = softplus(dt_r @ dt_proj_w + b), LDS-tiled (R13/R16-verbatim): 64m x 48d.
// ---------------------------------------------------------------------------
__global__ __launch_bounds__(256)
void dt_kernel(const float* __restrict__ x_dbl, const float* __restrict__ dtw,
               const float* __restrict__ dtb, bf16* __restrict__ dt_t)
{
    __shared__ float xs[64 * 25];
    __shared__ float ws[24 * 48];
    const int tid = threadIdx.x;
    const int m0 = blockIdx.x * 64;
    const int d0 = blockIdx.y * 48;
#pragma unroll
    for (int i = 0; i < 6; i++) {
        int idx = tid + 256 * i;        // < 1536 = 64*24
        int r_ = idx / 24, cc = idx % 24;
        xs[r_ * 25 + cc] = x_dbl[(size_t)(m0 + r_) * 56 + cc];
    }
#pragma unroll
    for (int i = 0; i < 5; i++) {
        int idx = tid + 256 * i;
        if (idx < 24 * 48) {
            int r_ = idx / 48, dd = idx % 48;
            ws[idx] = dtw[r_ * D_INNER + d0 + dd];
        }
    }
    __syncthreads();
#pragma unroll
    for (int i = 0; i < 12; i++) {
        int o = tid + 256 * i;          // < 3072 = 64*48
        int mloc = o & 63, dd = o >> 6; // dd wave-uniform
        float acc = dtb[d0 + dd];
#pragma unroll
        for (int r_ = 0; r_ < 24; r_++)
            acc += xs[mloc * 25 + r_] * ws[r_ * 48 + dd];
        float sp = fmaxf(acc, 0.f) + log1pf(__expf(-fabsf(acc)));
        dt_t[(size_t)(d0 + dd) * ML + m0 + mloc] = __float2bfloat16(sp);
    }
}

// ---------------------------------------------------------------------------
// Chunk-parallel selective scan. R22-green structure; ONLY change: phase-2
// Kogge-Stone moved in-wave. Block = 16 waves = D_STATE, so wave w owns
// state n=w with lane=chunk: 64-chunk (P,h) scan becomes 6 __shfl_up steps
// in wave64 lockstep, replacing 6 LDS iterations x 2 barriers (12 barriers
// -> 2). LDS padded [64][17] so transposed access sX[lane][wave] (stride 17
// floats) is bank-conflict-free (stride 16 = 32-way aliased, m136).
// ---------------------------------------------------------------------------
__global__ __launch_bounds__(1024)
void scan_kernel(const bf16* __restrict__ dt_t, const bf16* __restrict__ xp_t,
                 const float* __restrict__ x_dbl, const bf16* __restrict__ zs_t,
                 const float* __restrict__ A_log, const float* __restrict__ Dp,
                 bf16* __restrict__ y_t)
{
    __shared__ float sP[NCHUNK][D_STATE + 1];
    __shared__ float sH[NCHUNK][D_STATE + 1];
    const int tid = threadIdx.x;
    const int c = tid >> 4;           // chunk 0..63
    const int n = tid & 15;           // state 0..15
    const int g = blockIdx.x;         // (b,d)
    const int b = g / D_INNER;
    const int d = g % D_INNER;
    const float A = -__expf(A_log[d * D_STATE + n]);
    const size_t base_t = (size_t)d * ML + (size_t)b * L_SEQ + (size_t)c * CHLEN;
    const size_t base_m = (size_t)b * L_SEQ + (size_t)c * CHLEN;

    float h = 0.f, P = 1.f;
#pragma unroll
    for (int g2 = 0; g2 < 2; g2++) {
        bf16x8 vdt0 = *(const bf16x8*)&dt_t[base_t + g2 * 16];
        bf16x8 vdt1 = *(const bf16x8*)&dt_t[base_t + g2 * 16 + 8];
        bf16x8 vxp0 = *(const bf16x8*)&xp_t[base_t + g2 * 16];
        bf16x8 vxp1 = *(const bf16x8*)&xp_t[base_t + g2 * 16 + 8];
#pragma unroll
        for (int k = 0; k < 16; k++) {
            const int j = g2 * 16 + k;
            short sdt = (k < 8) ? vdt0[k & 7] : vdt1[k & 7];
            short sxp = (k < 8) ? vxp0[k & 7] : vxp1[k & 7];
            float dtv = __uint_as_float(((unsigned)(unsigned short)sdt) << 16);
            float xpv = __uint_as_float(((unsigned)(unsigned short)sxp) << 16);
            float Bn  = x_dbl[(base_m + j) * 56 + DT_RANK + n];
            float aj = __expf(dtv * A);
            h = aj * h + Bn * (dtv * xpv);
            P *= aj;
        }
    }
    sP[c][n] = P;
    sH[c][n] = h;
    __syncthreads();

    // Phase 2: in-wave Kogge-Stone. Wave w (of 16) scans the 64 chunks of
    // state n=w; lane = chunk. Composition: h = p*h_prev + h; p = p*p_prev.
    {
        const int wv = tid >> 6;      // wave id 0..15 == state
        const int ln = tid & 63;      // lane == chunk
        float p = sP[ln][wv];
        float hh = sH[ln][wv];
#pragma unroll
        for (int s = 1; s < NCHUNK; s <<= 1) {
            float p2 = __shfl_up(p, s);
            float h2 = __shfl_up(hh, s);
            if (ln >= s) { hh = p * h2 + hh; p = p * p2; }
        }
        sP[ln][wv] = p;
        sH[ln][wv] = hh;
    }
    __syncthreads();
    const float hinit = (c == 0) ? 0.f : sH[c - 1][n];

    // Phase 3: corrected re-scan + butterfly reduce + select-latch store
    const float Dd = Dp[d];
    h = hinit;
#pragma unroll
    for (int g2 = 0; g2 < 2; g2++) {
        bf16x8 vdt0 = *(const bf16x8*)&dt_t[base_t + g2 * 16];
        bf16x8 vdt1 = *(const bf16x8*)&dt_t[base_t + g2 * 16 + 8];
        bf16x8 vxp0 = *(const bf16x8*)&xp_t[base_t + g2 * 16];
        bf16x8 vxp1 = *(const bf16x8*)&xp_t[base_t + g2 * 16 + 8];
        float ymine = 0.f, xmine = 0.f;
#pragma unroll
        for (int k = 0; k < 16; k++) {
            const int j = g2 * 16 + k;
            short sdt = (k < 8) ? vdt0[k & 7] : vdt1[k & 7];
            short sxp = (k < 8) ? vxp0[k & 7] : vxp1[k & 7];
            float dtv = __uint_as_float(((unsigned)(unsigned short)sdt) << 16);
            float xpv = __uint_as_float(((unsigned)(unsigned short)sxp) << 16);
            float Bn  = x_dbl[(base_m + j) * 56 + DT_RANK + n];
            float aj = __expf(dtv * A);
            h = aj * h + Bn * (dtv * xpv);
            float Cn = x_dbl[(base_m + j) * 56 + DT_RANK + D_STATE + n];
            float yv = h * Cn;
            yv += __shfl_xor(yv, 1);
            yv += __shfl_xor(yv, 2);
            yv += __shfl_xor(yv, 4);
            yv += __shfl_xor(yv, 8);
            // all 16 lanes hold the full sum; lane n keeps step g2*16+n
            ymine = (k == n) ? yv : ymine;
            xmine = (k == n) ? xpv : xmine;
        }
        const int j = g2 * 16 + n;
        float zsv = __bfloat162float(zs_t[base_t + j]);
        y_t[base_t + j] = __float2bfloat16((ymine + xmine * Dd) * zsv);
    }
}

// ---------------------------------------------------------------------------
extern "C" void kernel_launch(void* const* d_in, const int* in_sizes, int n_in,
                              void* d_out, int out_size, void* d_ws, size_t ws_size,
                              hipStream_t stream)
{
    const float* x         = (const float*)d_in[0];
    const float* in_proj_w = (const float*)d_in[1];
    const float* conv_w    = (const float*)d_in[2];
    const float* conv_b    = (const float*)d_in[3];
    const float* x_proj_w  = (const float*)d_in[4];
    const float* dt_proj_w = (const float*)d_in[5];
    const float* dt_proj_b = (const float*)d_in[6];
    const float* A_log     = (const float*)d_in[7];
    const float* Dvec      = (const float*)d_in[8];
    const float* out_proj_w= (const float*)d_in[9];

    // workspace (all transposed [d][ml] bf16 except x_dbl): ~26.1 MB
    bf16* xp_raw_t = (bf16*)d_ws;                        // [768][ML] (reused as y_t)
    bf16* zs_t     = xp_raw_t + (size_t)ML * D_INNER;    // [768][ML] silu(z)
    bf16* xp_t     = zs_t     + (size_t)ML * D_INNER;    // [768][ML]
    bf16* dt_t     = xp_t     + (size_t)ML * D_INNER;    // [768][ML]
    float* x_dbl   = (float*)(dt_t + (size_t)ML * D_INNER); // [ML][56] fp32
    bf16* y_t      = xp_raw_t;                           // alias (dead after conv)

    dim3 blk(256);

    // 1) in_proj (64x64, proven): -> xp_raw_t | zs_t (transposed)
    gemm_mfma<0, 0><<<dim3(2 * D_INNER / 64, ML / 64), blk, 0, stream>>>(
        x, nullptr, in_proj_w, xp_raw_t, zs_t, nullptr, ML, 2 * D_INNER, D_MODEL);

    // 2) depthwise causal conv + silu (8 outputs/thread)
    conv_silu_kernel<<<dim3(ML / 2048, D_INNER), blk, 0, stream>>>(
        xp_raw_t, conv_w, conv_b, xp_t);

    // 3) x_proj, K-split x4 with fp32 atomics (x_dbl zeroed first)
    hipMemsetAsync(x_dbl, 0, (size_t)ML * 56 * sizeof(float), stream);
    gemm_xproj_split<<<dim3(4, ML / 64), blk, 0, stream>>>(
        xp_t, x_proj_w, x_dbl, ML, 56, D_INNER);

    // 4) dt_proj + softplus (LDS-tiled) -> dt_t
    dt_kernel<<<dim3(ML / 64, D_INNER / 48), blk, 0, stream>>>(
        x_dbl, dt_proj_w, dt_proj_b, dt_t);

    // 5) chunk-parallel selective scan -> y_t (aliases xp_raw_t)
    scan_kernel<<<B_SZ * D_INNER, 1024, 0, stream>>>(
        dt_t, xp_t, x_dbl, zs_t, A_log, Dvec, y_t);

    // 6) out_proj: A = y_t (transposed), W (768x384) -> d_out fp32
    gemm_mfma<1, 1><<<dim3(D_MODEL / 64, ML / 64), blk, 0, stream>>>(
        nullptr, y_t, out_proj_w, nullptr, nullptr, (float*)d_out, ML, D_MODEL, D_INNER);
}

// Round 24
// 239.341 us; speedup vs baseline: 1.0919x; 1.0151x over previous
//
#include <hip/hip_runtime.h>
#include <hip/hip_bf16.h>

#define B_SZ    2
#define L_SEQ   2048
#define D_MODEL 384
#define D_INNER 768
#define D_STATE 16
#define DT_RANK 24
#define ML      (B_SZ * L_SEQ)   // 4096 rows
#define NCHUNK  64
#define CHLEN   (L_SEQ / NCHUNK) // 32

typedef __hip_bfloat16 bf16;
typedef __attribute__((ext_vector_type(8))) short bf16x8;
typedef __attribute__((ext_vector_type(4))) float f32x4;
typedef __attribute__((ext_vector_type(8))) float f32x8;

// ---------------------------------------------------------------------------
// MFMA bf16 GEMM (R12/R14/R16-verbatim, green). C(MxN) = A(MxK) * W(KxN).
// AMODE 0: A fp32 row-major [M][K] (in_proj).  AMODE 1: A bf16 transposed [K][M].
// 256 thr / 4 waves; tile 64x64, BK=64; wave = 32x32 via 2x2 16x16x32 MFMA.
// EPI 0: in_proj split, transposed: outb0[n][m]=xp_raw, outb1[n-768][m]=silu(z)
// EPI 1: outf = fp32 C row-major (ld=N, guard n<N)
// ---------------------------------------------------------------------------
template<int EPI, int AMODE>
__global__ __launch_bounds__(256)
void gemm_mfma(const float* __restrict__ Af, const bf16* __restrict__ At,
               const float* __restrict__ W,
               bf16* __restrict__ outb0, bf16* __restrict__ outb1,
               float* __restrict__ outf, int M, int N, int K)
{
    __shared__ __attribute__((aligned(16))) short As[64][72];
    __shared__ __attribute__((aligned(16))) short Bs[64][72];
    const int tid  = threadIdx.x;
    const int lane = tid & 63;
    const int wave = tid >> 6;
    const int wm   = (wave & 1) * 32;
    const int wn   = (wave >> 1) * 32;
    const int m0   = blockIdx.y * 64;
    const int n0   = blockIdx.x * 64;

    f32x4 acc[2][2];
#pragma unroll
    for (int i = 0; i < 2; i++)
#pragma unroll
        for (int j = 0; j < 2; j++)
#pragma unroll
            for (int r = 0; r < 4; r++) acc[i][j][r] = 0.f;

    for (int kt = 0; kt < K; kt += 64) {
        __syncthreads();
        // Stage A tile 64x64
#pragma unroll
        for (int i = 0; i < 2; i++) {
            int c = tid + 256 * i;
            if (AMODE == 0) {                    // fp32 row-major
                int m = c >> 3, k8 = (c & 7) * 8;
                f32x8 a = *(const f32x8*)&Af[(size_t)(m0 + m) * K + kt + k8];
                bf16x8 h;
#pragma unroll
                for (int j = 0; j < 8; j++)
                    h[j] = (short)__bfloat16_as_ushort(__float2bfloat16(a[j]));
                *(bf16x8*)&As[m][k8] = h;
            } else {                             // bf16 transposed [K][M]
                int m8 = (c & 7) * 8, k = c >> 3;
                bf16x8 a = *(const bf16x8*)&At[(size_t)(kt + k) * M + m0 + m8];
#pragma unroll
                for (int j = 0; j < 8; j++) As[m8 + j][k] = a[j];
            }
        }
        // Stage W tile 64x64 transposed into Bs[n][k], fp32 -> bf16
#pragma unroll
        for (int i = 0; i < 2; i++) {
            int c = tid + 256 * i;
            int n8 = (c & 7) * 8, k = c >> 3;
            if (n0 + n8 + 8 <= N) {
                f32x8 w = *(const f32x8*)&W[(size_t)(kt + k) * N + n0 + n8];
#pragma unroll
                for (int j = 0; j < 8; j++)
                    Bs[n8 + j][k] = (short)__bfloat16_as_ushort(__float2bfloat16(w[j]));
            } else {
#pragma unroll
                for (int j = 0; j < 8; j++) Bs[n8 + j][k] = 0;
            }
        }
        __syncthreads();
#pragma unroll
        for (int ks = 0; ks < 2; ks++) {
            int kb = ks * 32 + (lane >> 4) * 8;
            bf16x8 a0 = *(const bf16x8*)&As[wm + (lane & 15)][kb];
            bf16x8 a1 = *(const bf16x8*)&As[wm + 16 + (lane & 15)][kb];
            bf16x8 b0 = *(const bf16x8*)&Bs[wn + (lane & 15)][kb];
            bf16x8 b1 = *(const bf16x8*)&Bs[wn + 16 + (lane & 15)][kb];
            acc[0][0] = __builtin_amdgcn_mfma_f32_16x16x32_bf16(a0, b0, acc[0][0], 0, 0, 0);
            acc[0][1] = __builtin_amdgcn_mfma_f32_16x16x32_bf16(a0, b1, acc[0][1], 0, 0, 0);
            acc[1][0] = __builtin_amdgcn_mfma_f32_16x16x32_bf16(a1, b0, acc[1][0], 0, 0, 0);
            acc[1][1] = __builtin_amdgcn_mfma_f32_16x16x32_bf16(a1, b1, acc[1][1], 0, 0, 0);
        }
    }

#pragma unroll
    for (int am = 0; am < 2; am++)
#pragma unroll
        for (int bn = 0; bn < 2; bn++)
#pragma unroll
            for (int r = 0; r < 4; r++) {
                int m = m0 + wm + am * 16 + (lane >> 4) * 4 + r;
                int n = n0 + wn + bn * 16 + (lane & 15);
                float v = acc[am][bn][r];
                if (EPI == 0) {
                    if (n < D_INNER)
                        outb0[(size_t)n * ML + m] = __float2bfloat16(v);
                    else
                        outb1[(size_t)(n - D_INNER) * ML + m] =
                            __float2bfloat16(v / (1.f + __expf(-v)));
                } else {
                    if (n < N) outf[(size_t)m * N + n] = v;
                }
            }
}

// ---------------------------------------------------------------------------
// x_proj GEMM with K-split x4 (R14/R16-verbatim, green): grid (4, ML/64).
// Partial over K in [kc*192, kc*192+192), atomicAdd fp32 into x_dbl.
// ---------------------------------------------------------------------------
__global__ __launch_bounds__(256)
void gemm_xproj_split(const bf16* __restrict__ At, const float* __restrict__ W,
                      float* __restrict__ outf, int M, int N, int K)
{
    __shared__ __attribute__((aligned(16))) short As[64][72];
    __shared__ __attribute__((aligned(16))) short Bs[64][72];
    const int tid  = threadIdx.x;
    const int lane = tid & 63;
    const int wave = tid >> 6;
    const int wm   = (wave & 1) * 32;
    const int wn   = (wave >> 1) * 32;
    const int m0   = blockIdx.y * 64;
    const int k0   = blockIdx.x * (768 / 4);     // 192-wide K chunk

    f32x4 acc[2][2];
#pragma unroll
    for (int i = 0; i < 2; i++)
#pragma unroll
        for (int j = 0; j < 2; j++)
#pragma unroll
            for (int r = 0; r < 4; r++) acc[i][j][r] = 0.f;

    for (int kt = k0; kt < k0 + 192; kt += 64) {
        __syncthreads();
#pragma unroll
        for (int i = 0; i < 2; i++) {
            int c = tid + 256 * i;
            int m8 = (c & 7) * 8, k = c >> 3;
            bf16x8 a = *(const bf16x8*)&At[(size_t)(kt + k) * M + m0 + m8];
#pragma unroll
            for (int j = 0; j < 8; j++) As[m8 + j][k] = a[j];
        }
#pragma unroll
        for (int i = 0; i < 2; i++) {
            int c = tid + 256 * i;
            int n8 = (c & 7) * 8, k = c >> 3;
            if (n8 + 8 <= N) {
                f32x8 w = *(const f32x8*)&W[(size_t)(kt + k) * N + n8];
#pragma unroll
                for (int j = 0; j < 8; j++)
                    Bs[n8 + j][k] = (short)__bfloat16_as_ushort(__float2bfloat16(w[j]));
            } else {
#pragma unroll
                for (int j = 0; j < 8; j++) Bs[n8 + j][k] = 0;
            }
        }
        __syncthreads();
#pragma unroll
        for (int ks = 0; ks < 2; ks++) {
            int kb = ks * 32 + (lane >> 4) * 8;
            bf16x8 a0 = *(const bf16x8*)&As[wm + (lane & 15)][kb];
            bf16x8 a1 = *(const bf16x8*)&As[wm + 16 + (lane & 15)][kb];
            bf16x8 b0 = *(const bf16x8*)&Bs[wn + (lane & 15)][kb];
            bf16x8 b1 = *(const bf16x8*)&Bs[wn + 16 + (lane & 15)][kb];
            acc[0][0] = __builtin_amdgcn_mfma_f32_16x16x32_bf16(a0, b0, acc[0][0], 0, 0, 0);
            acc[0][1] = __builtin_amdgcn_mfma_f32_16x16x32_bf16(a0, b1, acc[0][1], 0, 0, 0);
            acc[1][0] = __builtin_amdgcn_mfma_f32_16x16x32_bf16(a1, b0, acc[1][0], 0, 0, 0);
            acc[1][1] = __builtin_amdgcn_mfma_f32_16x16x32_bf16(a1, b1, acc[1][1], 0, 0, 0);
        }
    }

#pragma unroll
    for (int am = 0; am < 2; am++)
#pragma unroll
        for (int bn = 0; bn < 2; bn++)
#pragma unroll
            for (int r = 0; r < 4; r++) {
                int m = m0 + wm + am * 16 + (lane >> 4) * 4 + r;
                int n = wn + bn * 16 + (lane & 15);
                if (n < N)
                    atomicAdd(&outf[(size_t)m * N + n], acc[am][bn][r]);
            }
}

// ---------------------------------------------------------------------------
// Causal depthwise conv (K=4) + bias + SiLU, 8 outputs/thread (R22-verbatim)
// + fused x_dbl zeroing (replaces the hipMemsetAsync dispatch; kernel-launch
// ordering on the stream guarantees completion before x_proj's atomics).
// grid (ML/2048, D_INNER): 393216 threads >= 229376 x_dbl elements.
// ---------------------------------------------------------------------------
__global__ __launch_bounds__(256)
void conv_silu_kernel(const bf16* __restrict__ xp_raw_t,
                      const float* __restrict__ cw, const float* __restrict__ cb,
                      bf16* __restrict__ xp_t, float* __restrict__ x_dbl_zero)
{
    // fused zeroing of x_dbl [ML][56] fp32
    {
        int gidx = (blockIdx.y * gridDim.x + blockIdx.x) * 256 + threadIdx.x;
        if (gidx < ML * 56) x_dbl_zero[gidx] = 0.f;
    }

    const int ml0 = (blockIdx.x * 256 + threadIdx.x) * 8;
    const int d   = blockIdx.y;
    const int l0  = ml0 & (L_SEQ - 1);           // 8-aligned; l0+7 < L_SEQ
    const size_t row = (size_t)d * ML;
    const float w0 = cw[d * 4 + 0], w1 = cw[d * 4 + 1],
                w2 = cw[d * 4 + 2], w3 = cw[d * 4 + 3], bias = cb[d];

    bf16x8 cur = *(const bf16x8*)&xp_raw_t[row + ml0];
    bf16x8 prev;
    if (ml0 != 0) prev = *(const bf16x8*)&xp_raw_t[row + ml0 - 8];
    else {
#pragma unroll
        for (int j = 0; j < 8; j++) prev[j] = 0;
    }
    float w[16];
#pragma unroll
    for (int k = 0; k < 8; k++) {
        w[k]     = __uint_as_float(((unsigned)(unsigned short)prev[k]) << 16);
        w[k + 8] = __uint_as_float(((unsigned)(unsigned short)cur[k]) << 16);
    }

    bf16x8 out;
#pragma unroll
    for (int o = 0; o < 8; o++) {
        int l = l0 + o;
        float s = bias;
        if (l >= 3) {
            s += w0 * w[5 + o] + w1 * w[6 + o] + w2 * w[7 + o] + w3 * w[8 + o];
        } else {
            if (l - 3 >= 0) s += w0 * w[5 + o];
            if (l - 2 >= 0) s += w1 * w[6 + o];
            if (l - 1 >= 0) s += w2 * w[7 + o];
            s += w3 * w[8 + o];
        }
        float act = s / (1.f + __expf(-s));
        out[o] = (short)__bfloat16_as_ushort(__float2bfloat16(act));
    }
    *(bf16x8*)&xp_t[row + ml0] = out;
}

// ---------------------------------------------------------------------------
// dt = softplus(dt_r @ dt_proj_w + b), LDS-tiled (R13/R16-verbatim): 64m x 48d.
// ---------------------------------------------------------------------------
__global__ __launch_bounds__(256)
void dt_kernel(const float* __restrict__ x_dbl, const float* __restrict__ dtw,
               const float* __restrict__ dtb, bf16* __restrict__ dt_t)
{
    __shared__ float xs[64 * 25];
    __shared__ float ws[24 * 48];
    const int tid = threadIdx.x;
    const int m0 = blockIdx.x * 64;
    const int d0 = blockIdx.y * 48;
#pragma unroll
    for (int i = 0; i < 6; i++) {
        int idx = tid + 256 * i;        // < 1536 = 64*24
        int r_ = idx / 24, cc = idx % 24;
        xs[r_ * 25 + cc] = x_dbl[(size_t)(m0 + r_) * 56 + cc];
    }
#pragma unroll
    for (int i = 0; i < 5; i++) {
        int idx = tid + 256 * i;
        if (idx < 24 * 48) {
            int r_ = idx / 48, dd = idx % 48;
            ws[idx] = dtw[r_ * D_INNER + d0 + dd];
        }
    }
    __syncthreads();
#pragma unroll
    for (int i = 0; i < 12; i++) {
        int o = tid + 256 * i;          // < 3072 = 64*48
        int mloc = o & 63, dd = o >> 6; // dd wave-uniform
        float acc = dtb[d0 + dd];
#pragma unroll
        for (int r_ = 0; r_ < 24; r_++)
            acc += xs[mloc * 25 + r_] * ws[r_ * 48 + dd];
        float sp = fmaxf(acc, 0.f) + log1pf(__expf(-fabsf(acc)));
        dt_t[(size_t)(d0 + dd) * ML + m0 + mloc] = __float2bfloat16(sp);
    }
}

// ---------------------------------------------------------------------------
// Chunk-parallel selective scan (R23-verbatim, green): bf16x8 group loads,
// in-wave Kogge-Stone phase 2 (6 shfl_up steps, 2 barriers total),
// butterfly reduce + select-latch epilogue.
// ---------------------------------------------------------------------------
__global__ __launch_bounds__(1024)
void scan_kernel(const bf16* __restrict__ dt_t, const bf16* __restrict__ xp_t,
                 const float* __restrict__ x_dbl, const bf16* __restrict__ zs_t,
                 const float* __restrict__ A_log, const float* __restrict__ Dp,
                 bf16* __restrict__ y_t)
{
    __shared__ float sP[NCHUNK][D_STATE + 1];
    __shared__ float sH[NCHUNK][D_STATE + 1];
    const int tid = threadIdx.x;
    const int c = tid >> 4;           // chunk 0..63
    const int n = tid & 15;           // state 0..15
    const int g = blockIdx.x;         // (b,d)
    const int b = g / D_INNER;
    const int d = g % D_INNER;
    const float A = -__expf(A_log[d * D_STATE + n]);
    const size_t base_t = (size_t)d * ML + (size_t)b * L_SEQ + (size_t)c * CHLEN;
    const size_t base_m = (size_t)b * L_SEQ + (size_t)c * CHLEN;

    float h = 0.f, P = 1.f;
#pragma unroll
    for (int g2 = 0; g2 < 2; g2++) {
        bf16x8 vdt0 = *(const bf16x8*)&dt_t[base_t + g2 * 16];
        bf16x8 vdt1 = *(const bf16x8*)&dt_t[base_t + g2 * 16 + 8];
        bf16x8 vxp0 = *(const bf16x8*)&xp_t[base_t + g2 * 16];
        bf16x8 vxp1 = *(const bf16x8*)&xp_t[base_t + g2 * 16 + 8];
#pragma unroll
        for (int k = 0; k < 16; k++) {
            const int j = g2 * 16 + k;
            short sdt = (k < 8) ? vdt0[k & 7] : vdt1[k & 7];
            short sxp = (k < 8) ? vxp0[k & 7] : vxp1[k & 7];
            float dtv = __uint_as_float(((unsigned)(unsigned short)sdt) << 16);
            float xpv = __uint_as_float(((unsigned)(unsigned short)sxp) << 16);
            float Bn  = x_dbl[(base_m + j) * 56 + DT_RANK + n];
            float aj = __expf(dtv * A);
            h = aj * h + Bn * (dtv * xpv);
            P *= aj;
        }
    }
    sP[c][n] = P;
    sH[c][n] = h;
    __syncthreads();

    // Phase 2: in-wave Kogge-Stone. Wave w (of 16) scans the 64 chunks of
    // state n=w; lane = chunk. Composition: h = p*h_prev + h; p = p*p_prev.
    {
        const int wv = tid >> 6;      // wave id 0..15 == state
        const int ln = tid & 63;      // lane == chunk
        float p = sP[ln][wv];
        float hh = sH[ln][wv];
#pragma unroll
        for (int s = 1; s < NCHUNK; s <<= 1) {
            float p2 = __shfl_up(p, s);
            float h2 = __shfl_up(hh, s);
            if (ln >= s) { hh = p * h2 + hh; p = p * p2; }
        }
        sP[ln][wv] = p;
        sH[ln][wv] = hh;
    }
    __syncthreads();
    const float hinit = (c == 0) ? 0.f : sH[c - 1][n];

    // Phase 3: corrected re-scan + butterfly reduce + select-latch store
    const float Dd = Dp[d];
    h = hinit;
#pragma unroll
    for (int g2 = 0; g2 < 2; g2++) {
        bf16x8 vdt0 = *(const bf16x8*)&dt_t[base_t + g2 * 16];
        bf16x8 vdt1 = *(const bf16x8*)&dt_t[base_t + g2 * 16 + 8];
        bf16x8 vxp0 = *(const bf16x8*)&xp_t[base_t + g2 * 16];
        bf16x8 vxp1 = *(const bf16x8*)&xp_t[base_t + g2 * 16 + 8];
        float ymine = 0.f, xmine = 0.f;
#pragma unroll
        for (int k = 0; k < 16; k++) {
            const int j = g2 * 16 + k;
            short sdt = (k < 8) ? vdt0[k & 7] : vdt1[k & 7];
            short sxp = (k < 8) ? vxp0[k & 7] : vxp1[k & 7];
            float dtv = __uint_as_float(((unsigned)(unsigned short)sdt) << 16);
            float xpv = __uint_as_float(((unsigned)(unsigned short)sxp) << 16);
            float Bn  = x_dbl[(base_m + j) * 56 + DT_RANK + n];
            float aj = __expf(dtv * A);
            h = aj * h + Bn * (dtv * xpv);
            float Cn = x_dbl[(base_m + j) * 56 + DT_RANK + D_STATE + n];
            float yv = h * Cn;
            yv += __shfl_xor(yv, 1);
            yv += __shfl_xor(yv, 2);
            yv += __shfl_xor(yv, 4);
            yv += __shfl_xor(yv, 8);
            // all 16 lanes hold the full sum; lane n keeps step g2*16+n
            ymine = (k == n) ? yv : ymine;
            xmine = (k == n) ? xpv : xmine;
        }
        const int j = g2 * 16 + n;
        float zsv = __bfloat162float(zs_t[base_t + j]);
        y_t[base_t + j] = __float2bfloat16((ymine + xmine * Dd) * zsv);
    }
}

// ---------------------------------------------------------------------------
extern "C" void kernel_launch(void* const* d_in, const int* in_sizes, int n_in,
                              void* d_out, int out_size, void* d_ws, size_t ws_size,
                              hipStream_t stream)
{
    const float* x         = (const float*)d_in[0];
    const float* in_proj_w = (const float*)d_in[1];
    const float* conv_w    = (const float*)d_in[2];
    const float* conv_b    = (const float*)d_in[3];
    const float* x_proj_w  = (const float*)d_in[4];
    const float* dt_proj_w = (const float*)d_in[5];
    const float* dt_proj_b = (const float*)d_in[6];
    const float* A_log     = (const float*)d_in[7];
    const float* Dvec      = (const float*)d_in[8];
    const float* out_proj_w= (const float*)d_in[9];

    // workspace (all transposed [d][ml] bf16 except x_dbl): ~26.1 MB
    bf16* xp_raw_t = (bf16*)d_ws;                        // [768][ML] (reused as y_t)
    bf16* zs_t     = xp_raw_t + (size_t)ML * D_INNER;    // [768][ML] silu(z)
    bf16* xp_t     = zs_t     + (size_t)ML * D_INNER;    // [768][ML]
    bf16* dt_t     = xp_t     + (size_t)ML * D_INNER;    // [768][ML]
    float* x_dbl   = (float*)(dt_t + (size_t)ML * D_INNER); // [ML][56] fp32
    bf16* y_t      = xp_raw_t;                           // alias (dead after conv)

    dim3 blk(256);

    // 1) in_proj (64x64, proven): -> xp_raw_t | zs_t (transposed)
    gemm_mfma<0, 0><<<dim3(2 * D_INNER / 64, ML / 64), blk, 0, stream>>>(
        x, nullptr, in_proj_w, xp_raw_t, zs_t, nullptr, ML, 2 * D_INNER, D_MODEL);

    // 2) depthwise causal conv + silu (8 outputs/thread) + fused x_dbl zeroing
    conv_silu_kernel<<<dim3(ML / 2048, D_INNER), blk, 0, stream>>>(
        xp_raw_t, conv_w, conv_b, xp_t, x_dbl);

    // 3) x_proj, K-split x4 with fp32 atomics (x_dbl zeroed by conv kernel)
    gemm_xproj_split<<<dim3(4, ML / 64), blk, 0, stream>>>(
        xp_t, x_proj_w, x_dbl, ML, 56, D_INNER);

    // 4) dt_proj + softplus (LDS-tiled) -> dt_t
    dt_kernel<<<dim3(ML / 64, D_INNER / 48), blk, 0, stream>>>(
        x_dbl, dt_proj_w, dt_proj_b, dt_t);

    // 5) chunk-parallel selective scan -> y_t (aliases xp_raw_t)
    scan_kernel<<<B_SZ * D_INNER, 1024, 0, stream>>>(
        dt_t, xp_t, x_dbl, zs_t, A_log, Dvec, y_t);

    // 6) out_proj: A = y_t (transposed), W (768x384) -> d_out fp32
    gemm_mfma<1, 1><<<dim3(D_MODEL / 64, ML / 64), blk, 0, stream>>>(
        nullptr, y_t, out_proj_w, nullptr, nullptr, (float*)d_out, ML, D_MODEL, D_INNER);
}